// Round 3
// baseline (266.045 us; speedup 1.0000x reference)
//
#include <hip/hip_runtime.h>
#include <hip/hip_bf16.h>

// Problem constants
#define H 1024
#define NHEAD 16
#define HDIM 64
#define SEQ 2048
#define BATCH 2
#define M_TOT (BATCH * SEQ) // 4096 tokens
#define NQKV 3072           // fused QKV output cols

typedef __attribute__((ext_vector_type(8))) short bf16x8;  // 8 bf16 = 4 VGPRs (MFMA A/B frag)
typedef __attribute__((ext_vector_type(4))) float f32x4;   // 16x16 MFMA C/D frag
typedef __attribute__((ext_vector_type(16))) float f32x16; // 32x32 MFMA C/D frag

// (1/sqrt(HDIM)) * log2(e), folded into Q at the QKV-GEMM epilogue
#define C2_SCALE 0.18033688f

__device__ __forceinline__ unsigned short f2bf(float f) {
  union { float f; unsigned int u; } a;
  a.f = f;
  unsigned int u = a.u;
  return (unsigned short)((u + 0x7fffu + ((u >> 16) & 1u)) >> 16); // RNE
}

// packed f32x2 -> bf16x2 (v_cvt_pk_bf16_f32), low short = first arg
__device__ __forceinline__ unsigned int pkbf(float a, float b) {
  union { __hip_bfloat162 h; unsigned int u; } cv;
  cv.h = __float22bfloat162_rn(float2{a, b});
  return cv.u;
}

__device__ __forceinline__ float fast_exp2(float x) {
#if defined(__has_builtin) && __has_builtin(__builtin_amdgcn_exp2f)
  return __builtin_amdgcn_exp2f(x);
#else
  return exp2f(x);
#endif
}

// async global->LDS, 16B per lane. LDS dest is wave-uniform base + lane*16.
typedef const __attribute__((address_space(1))) void* gas1_t;
typedef __attribute__((address_space(3))) void* las3_t;
__device__ __forceinline__ void gload16(const void* g, void* l) {
  __builtin_amdgcn_global_load_lds((gas1_t)(unsigned long long)g,
                                   (las3_t)(unsigned int)(unsigned long long)l,
                                   16, 0, 0);
}

// ---------------------------------------------------------------------------
// Kernel 1 (fused): LayerNorm rows (blocks 0..4095) + weight bf16 cast
// (blocks 4096..8191).
// ---------------------------------------------------------------------------
__global__ __launch_bounds__(256) void ln_cast_kernel(const float* __restrict__ x,
                                                      const float* __restrict__ gamma,
                                                      const float* __restrict__ beta,
                                                      unsigned short* __restrict__ xn,
                                                      const float* __restrict__ w0,
                                                      const float* __restrict__ w1,
                                                      const float* __restrict__ w2,
                                                      const float* __restrict__ w3,
                                                      unsigned short* __restrict__ wdst) {
  const int t = threadIdx.x;
  if (blockIdx.x >= M_TOT) {
    const int cb = blockIdx.x - M_TOT;   // 0..4095
    const int y = cb >> 10;              // matrix index 0..3
    const float* s = (y == 0) ? w0 : (y == 1) ? w1 : (y == 2) ? w2 : w3;
    const int i = (cb & 1023) * 256 + t; // float4 index within matrix
    const float4 v = ((const float4*)s)[i];
    ushort4 o;
    o.x = f2bf(v.x);
    o.y = f2bf(v.y);
    o.z = f2bf(v.z);
    o.w = f2bf(v.w);
    ((ushort4*)(wdst + (size_t)y * H * H))[i] = o;
    return;
  }
  const int row = blockIdx.x;
  const float* xr = x + (size_t)row * H;
  float4 v = ((const float4*)xr)[t];
  float s = v.x + v.y + v.z + v.w;
  float s2 = v.x * v.x + v.y * v.y + v.z * v.z + v.w * v.w;
#pragma unroll
  for (int o = 32; o; o >>= 1) {
    s += __shfl_xor(s, o, 64);
    s2 += __shfl_xor(s2, o, 64);
  }
  __shared__ float red[8];
  const int wave = t >> 6;
  if ((t & 63) == 0) {
    red[wave] = s;
    red[wave + 4] = s2;
  }
  __syncthreads();
  const float ts = red[0] + red[1] + red[2] + red[3];
  const float ts2 = red[4] + red[5] + red[6] + red[7];
  const float mu = ts * (1.0f / (float)H);
  const float var = ts2 * (1.0f / (float)H) - mu * mu;
  const float rstd = rsqrtf(var + 1e-5f);
  const float4 g = ((const float4*)gamma)[t];
  const float4 b = ((const float4*)beta)[t];
  ushort4 o;
  o.x = f2bf((v.x - mu) * rstd * g.x + b.x);
  o.y = f2bf((v.y - mu) * rstd * g.y + b.y);
  o.z = f2bf((v.z - mu) * rstd * g.z + b.z);
  o.w = f2bf((v.w - mu) * rstd * g.w + b.w);
  ((ushort4*)(xn + (size_t)row * H))[t] = o;
}

// ---------------------------------------------------------------------------
// 128x128x(BK=32) bf16 MFMA GEMM (16x16x32, 32 KB LDS, double-buffered,
// one barrier per K-iter, 4 blocks/CU) with XCD-AWARE 1-D GRID:
//   xcd = id & 7; each XCD owns NPX consecutive N-blocks (W-slice stays in
//   its 4 MB L2); M-blocks iterate within the XCD.
// EPI=0 (NPX=3): QKV epilogue. Q cols (<1024) scaled by C2_SCALE.
//        cols<2048 -> qk natural; cols>=2048 -> V transposed vt[b][h*64+d][s].
// EPI=1 (NPX=1): proj epilogue -> fp32 out = acc + bo[col] + x (residual).
// ---------------------------------------------------------------------------
template <int EPI, int NPX>
__global__ __launch_bounds__(256, 4) void gemm128(const unsigned short* __restrict__ A,
                                                  const unsigned short* __restrict__ W,
                                                  unsigned short* __restrict__ qk,
                                                  unsigned short* __restrict__ vt,
                                                  const float* __restrict__ bo,
                                                  const float* __restrict__ x,
                                                  float* __restrict__ out) {
  const int id = blockIdx.x;
  const int xcd = id & 7;
  const int r = id >> 3;
  const int nb = xcd * NPX + (r % NPX);
  const int mb = r / NPX;
  const int m0 = mb * 128;
  const int n0 = nb * 128;
  const int tid = threadIdx.x;
  const int wave = tid >> 6;
  const int lane = tid & 63;
  const int l16 = lane & 15;
  const int quad = lane >> 4;
  const int wx = wave & 1, wy = wave >> 1;

  __shared__ __align__(16) unsigned short As[2][128 * 32];
  __shared__ __align__(16) unsigned short Bs[2][128 * 32];

  // staging: wave stages 32 rows (2 gload16 instrs per matrix)
  const int sub = lane >> 2;       // row within 16-row group
  const int kcol = (lane & 3) * 8; // 4 lanes cover 32 cols
  const unsigned short* ag = A + (size_t)(m0 + wave * 32 + sub) * H + kcol;
  const unsigned short* bg = W + (size_t)(n0 + wave * 32 + sub) * H + kcol;
  const int lofs = wave * 32 * 32;

  f32x4 acc[4][4] = {};

  // prologue: stage k0=0 into buffer 0
  gload16(ag, &As[0][lofs]);
  gload16(ag + 16 * H, &As[0][lofs + 16 * 32]);
  gload16(bg, &Bs[0][lofs]);
  gload16(bg + 16 * H, &Bs[0][lofs + 16 * 32]);

  for (int it = 0; it < H / 32; it++) {
    const int bi = it & 1;
    __syncthreads(); // drains buf[bi] loads (issued a full iter ago)
    if (it + 1 < H / 32) {
      const int k1 = (it + 1) * 32;
      gload16(ag + k1, &As[bi ^ 1][lofs]);
      gload16(ag + k1 + 16 * H, &As[bi ^ 1][lofs + 16 * 32]);
      gload16(bg + k1, &Bs[bi ^ 1][lofs]);
      gload16(bg + k1 + 16 * H, &Bs[bi ^ 1][lofs + 16 * 32]);
    }
    bf16x8 af[4], bf[4];
#pragma unroll
    for (int t = 0; t < 4; t++) {
      af[t] = *(const bf16x8*)&As[bi][(wy * 64 + t * 16 + l16) * 32 + quad * 8];
      bf[t] = *(const bf16x8*)&Bs[bi][(wx * 64 + t * 16 + l16) * 32 + quad * 8];
    }
#pragma unroll
    for (int i = 0; i < 4; i++)
#pragma unroll
      for (int j = 0; j < 4; j++)
        acc[i][j] = __builtin_amdgcn_mfma_f32_16x16x32_bf16(af[i], bf[j], acc[i][j], 0, 0, 0);
  }

  if (EPI == 0) {
#pragma unroll
    for (int j = 0; j < 4; j++) {
      const int cb = n0 + wx * 64 + j * 16; // wave-uniform tile col base
      if (cb < 2048) {
        const float qs = (cb < 1024) ? C2_SCALE : 1.0f;
#pragma unroll
        for (int i = 0; i < 4; i++) {
          const int row = m0 + wy * 64 + i * 16 + quad * 4;
#pragma unroll
          for (int r2 = 0; r2 < 4; r2++)
            qk[(size_t)(row + r2) * 2048 + cb + l16] = f2bf(acc[i][j][r2] * qs);
        }
      } else {
        const int n = cb + l16 - 2048; // h*64+d
#pragma unroll
        for (int i = 0; i < 4; i++) {
          const int row0 = m0 + wy * 64 + i * 16 + quad * 4;
          const int b = row0 >> 11;
          const int s = row0 & 2047;
          ushort4 p;
          p.x = f2bf(acc[i][j][0]);
          p.y = f2bf(acc[i][j][1]);
          p.z = f2bf(acc[i][j][2]);
          p.w = f2bf(acc[i][j][3]);
          *(ushort4*)&vt[((size_t)b * 1024 + n) * SEQ + s] = p;
        }
      }
    }
  } else {
#pragma unroll
    for (int j = 0; j < 4; j++) {
      const int col = n0 + wx * 64 + j * 16 + l16;
      const float bv = bo[col];
#pragma unroll
      for (int i = 0; i < 4; i++) {
        const int row = m0 + wy * 64 + i * 16 + quad * 4;
#pragma unroll
        for (int r2 = 0; r2 < 4; r2++) {
          const size_t idx = (size_t)(row + r2) * H + col;
          out[idx] = acc[i][j][r2] + bv + x[idx];
        }
      }
    }
  }
}

// ---------------------------------------------------------------------------
// Flash attention v7: 32x32x16 in-register-P formulation (v5) with NO LDS
// AND NO BARRIERS. K and V fragments are loaded DIRECTLY global->register
// (per-lane 16B loads; lanes l / l+32 merge to 32B; K/V slice is L2-resident
// per XCD via the swizzled grid). Register prefetch rotate:
//   - kf (K frags for iter t+1) issued right after QK(t) consumes them
//     (~350 cyc of softmax+PV before next use; covers L2 ~200 cyc).
//   - vf (V frags for iter t+1) issued right after PV(t) (full iter of slack).
// The compiler inserts counted vmcnt waits for register loads (the pipeline
// global_load_lds can't express). Each wave is fully independent.
// Grid: 512 blocks (128-row q-tiles), XCD-supertiled as in v5.
// ---------------------------------------------------------------------------
__global__ __launch_bounds__(256, 2) void attn_kernel(const unsigned short* __restrict__ qk,
                                                      const unsigned short* __restrict__ vt,
                                                      unsigned short* __restrict__ O) {
  const int id = blockIdx.x; // 512 blocks
  const int xcd = id & 7;
  const int slot = id >> 3;       // 0..63
  const int qt = slot & 15;       // q-tile within (b,h)
  const int g = slot >> 4;        // 0..3
  const int combo = xcd * 4 + g;  // 0..31
  const int h = combo & 15;
  const int b = combo >> 4;
  const int tid = threadIdx.x;
  const int wave = tid >> 6;
  const int lane = tid & 63;
  const int l31 = lane & 31;
  const int hi = lane >> 5;

  const unsigned short* Qbase = qk + (size_t)b * SEQ * 2048 + h * 64;
  const unsigned short* Kbase = qk + (size_t)b * SEQ * 2048 + 1024 + h * 64;
  const unsigned short* Vbase = vt + ((size_t)b * 1024 + h * 64) * SEQ;

  // Q fragments (B-operand, hoisted): B[n=l31 -> qrow][k=hi*8+e -> d in chunk kc]
  const int qrow = qt * 128 + wave * 32 + l31;
  bf16x8 aq[4];
#pragma unroll
  for (int kc = 0; kc < 4; kc++)
    aq[kc] = *(const bf16x8*)(Qbase + (size_t)qrow * 2048 + kc * 16 + hi * 8);

  // per-lane K/V fragment base pointers
  // K frag (A-op): row s = it*64 + mt*32 + l31, col d = kc*16 + hi*8
  const unsigned short* kp0 = Kbase + (size_t)l31 * 2048 + hi * 8;
  const unsigned short* kp1 = Kbase + (size_t)(32 + l31) * 2048 + hi * 8;
  // V frag (A-op): row d = dt*32 + l31, col s = it*64 + sc*16 + hi*8
  const unsigned short* vp0 = Vbase + (size_t)l31 * SEQ + hi * 8;
  const unsigned short* vp1 = Vbase + (size_t)(32 + l31) * SEQ + hi * 8;

  f32x16 o_acc[2] = {}; // [dt] O^T: col=l31=qrow, row=(reg&3)+8*(reg>>2)+4*hi -> d
  float lc[4] = {};     // partial denominators (4 chains)

  // prologue: load iter-0 K/V fragments
  bf16x8 kf[2][4]; // [mt][kc]
  bf16x8 vf[4][2]; // [sc][dt]
#pragma unroll
  for (int kc = 0; kc < 4; kc++) {
    kf[0][kc] = *(const bf16x8*)(kp0 + kc * 16);
    kf[1][kc] = *(const bf16x8*)(kp1 + kc * 16);
  }
#pragma unroll
  for (int sc = 0; sc < 4; sc++) {
    vf[sc][0] = *(const bf16x8*)(vp0 + sc * 16);
    vf[sc][1] = *(const bf16x8*)(vp1 + sc * 16);
  }

#pragma unroll 2
  for (int it = 0; it < SEQ / 64; it++) {
    const int itn = (it + 1 < SEQ / 64) ? it + 1 : (SEQ / 64 - 1); // clamped prefetch idx

    // S^T = K (A) @ Q^T (B): 2 m-tiles (s 0..31 / 32..63) x 4 k-chunks
    f32x16 s0 = {}, s1 = {};
#pragma unroll
    for (int kc = 0; kc < 4; kc++) {
      s0 = __builtin_amdgcn_mfma_f32_32x32x16_bf16(kf[0][kc], aq[kc], s0, 0, 0, 0);
      s1 = __builtin_amdgcn_mfma_f32_32x32x16_bf16(kf[1][kc], aq[kc], s1, 0, 0, 0);
    }

    // prefetch K frags for next iter (consumed after softmax+PV of this iter)
    {
      const size_t ko = (size_t)itn * (64 * 2048);
#pragma unroll
      for (int kc = 0; kc < 4; kc++) {
        kf[0][kc] = *(const bf16x8*)(kp0 + ko + kc * 16);
        kf[1][kc] = *(const bf16x8*)(kp1 + ko + kc * 16);
      }
    }

    // fixed-max softmax: p = exp2(s), all for qrow = l31; pack to bf16 pairs.
    // w[mt][gi] covers s = 32*mt + {2gi,2gi+1 pattern} + 4*hi
    unsigned int w[2][8];
    {
      float p[16];
#pragma unroll
      for (int r2 = 0; r2 < 16; r2++) p[r2] = fast_exp2(s0[r2]);
      lc[0] += ((p[0] + p[1]) + (p[2] + p[3])) + ((p[8] + p[9]) + (p[10] + p[11]));
      lc[1] += ((p[4] + p[5]) + (p[6] + p[7])) + ((p[12] + p[13]) + (p[14] + p[15]));
#pragma unroll
      for (int gi = 0; gi < 8; gi++) w[0][gi] = pkbf(p[2 * gi], p[2 * gi + 1]);
    }
    {
      float p[16];
#pragma unroll
      for (int r2 = 0; r2 < 16; r2++) p[r2] = fast_exp2(s1[r2]);
      lc[2] += ((p[0] + p[1]) + (p[2] + p[3])) + ((p[8] + p[9]) + (p[10] + p[11]));
      lc[3] += ((p[4] + p[5]) + (p[6] + p[7])) + ((p[12] + p[13]) + (p[14] + p[15]));
#pragma unroll
      for (int gi = 0; gi < 8; gi++) w[1][gi] = pkbf(p[2 * gi], p[2 * gi + 1]);
    }

    // O^T += V^T (A) @ P^T (B). Per s-chunk sc: two permlane32_swap build the
    // B-frag in-register (same derivation as v5).
#pragma unroll
    for (int sc = 0; sc < 4; sc++) {
      const int n0i = 2 * sc, n1i = 2 * sc + 1;
      const int mt0 = n0i >> 2, b0 = n0i & 3;
      const int mt1 = n1i >> 2, b1 = n1i & 3;
      const auto rA = __builtin_amdgcn_permlane32_swap(w[mt0][2 * b0], w[mt1][2 * b1],
                                                       false, false);
      const auto rB = __builtin_amdgcn_permlane32_swap(w[mt0][2 * b0 + 1], w[mt1][2 * b1 + 1],
                                                       false, false);
      union { unsigned int u[4]; bf16x8 v; } pb;
      pb.u[0] = rA[0]; // k = sc*16+hi*8 + {0,1}
      pb.u[1] = rB[0]; // + {2,3}
      pb.u[2] = rA[1]; // + {4,5}
      pb.u[3] = rB[1]; // + {6,7}
      o_acc[0] = __builtin_amdgcn_mfma_f32_32x32x16_bf16(vf[sc][0], pb.v, o_acc[0], 0, 0, 0);
      o_acc[1] = __builtin_amdgcn_mfma_f32_32x32x16_bf16(vf[sc][1], pb.v, o_acc[1], 0, 0, 0);
    }

    // prefetch V frags for next iter (full iteration of slack)
    {
      const size_t vo = (size_t)itn * 64;
#pragma unroll
      for (int sc = 0; sc < 4; sc++) {
        vf[sc][0] = *(const bf16x8*)(vp0 + vo + sc * 16);
        vf[sc][1] = *(const bf16x8*)(vp1 + vo + sc * 16);
      }
    }
  }

  // epilogue: lanes l and l|32 hold complementary s-subsets of the same qrow
  float lsum = (lc[0] + lc[1]) + (lc[2] + lc[3]);
  const float l_i = lsum + __shfl_xor(lsum, 32, 64);
  const float inv = 1.0f / l_i;
  unsigned short* orow = O + ((size_t)(b * SEQ + qrow)) * H + h * 64;
#pragma unroll
  for (int dt = 0; dt < 2; dt++)
#pragma unroll
    for (int rg = 0; rg < 4; rg++) {
      uint2 d;
      d.x = pkbf(o_acc[dt][4 * rg + 0] * inv, o_acc[dt][4 * rg + 1] * inv);
      d.y = pkbf(o_acc[dt][4 * rg + 2] * inv, o_acc[dt][4 * rg + 3] * inv);
      *(uint2*)&orow[dt * 32 + 8 * rg + 4 * hi] = d;
    }
}

// ---------------------------------------------------------------------------
extern "C" void kernel_launch(void* const* d_in, const int* in_sizes, int n_in,
                              void* d_out, int out_size, void* d_ws, size_t ws_size,
                              hipStream_t stream) {
  const float* x = (const float*)d_in[0];
  const float* Wq = (const float*)d_in[1];
  const float* Wk = (const float*)d_in[2];
  const float* Wv = (const float*)d_in[3];
  const float* Wo = (const float*)d_in[4];
  const float* bo = (const float*)d_in[5];
  const float* gamma = (const float*)d_in[6];
  const float* beta = (const float*)d_in[7];
  float* out = (float*)d_out;

  unsigned short* ws = (unsigned short*)d_ws;
  unsigned short* xn = ws;                              // 4096*1024
  unsigned short* wcat = xn + (size_t)M_TOT * H;        // 4*1024*1024 (Wq,Wk,Wv,Wo)
  unsigned short* wob = wcat + (size_t)3 * H * H;
  unsigned short* qkb = wcat + (size_t)4 * H * H;       // 4096*2048 (Q | K)
  unsigned short* vtb = qkb + (size_t)M_TOT * 2048;     // 2*1024*2048 (V^T)
  unsigned short* atb = vtb + (size_t)BATCH * H * SEQ;  // 4096*1024

  ln_cast_kernel<<<M_TOT + 4096, 256, 0, stream>>>(x, gamma, beta, xn, Wq, Wk, Wv, Wo,
                                                   wcat);
  // QKV: 32 M-blocks x 24 N-blocks, XCD-supertiled (3 N-blocks per XCD)
  gemm128<0, 3><<<(M_TOT / 128) * (NQKV / 128), 256, 0, stream>>>(
      xn, wcat, qkb, vtb, nullptr, nullptr, nullptr);
  // attn: 512 blocks (128-row q-tiles), XCD-supertiled (4 (b,h) combos per XCD)
  attn_kernel<<<(SEQ / 128) * NHEAD * BATCH, 256, 0, stream>>>(qkb, vtb, atb);
  // proj: 32 M-blocks x 8 N-blocks, XCD-supertiled (1 N-block per XCD)
  gemm128<1, 1><<<(M_TOT / 128) * (H / 128), 256, 0, stream>>>(
      atb, wob, nullptr, nullptr, bo, x, out);
}

// Round 4
// 194.202 us; speedup vs baseline: 1.3699x; 1.3699x over previous
//
#include <hip/hip_runtime.h>
#include <hip/hip_bf16.h>

// Problem constants
#define H 1024
#define NHEAD 16
#define HDIM 64
#define SEQ 2048
#define BATCH 2
#define M_TOT (BATCH * SEQ) // 4096 tokens
#define NQKV 3072           // fused QKV output cols

typedef __attribute__((ext_vector_type(8))) short bf16x8;  // 8 bf16 = 4 VGPRs (MFMA A/B frag)
typedef __attribute__((ext_vector_type(4))) float f32x4;   // 16x16 MFMA C/D frag
typedef __attribute__((ext_vector_type(16))) float f32x16; // 32x32 MFMA C/D frag

// (1/sqrt(HDIM)) * log2(e), folded into Q at the QKV-GEMM epilogue
#define C2_SCALE 0.18033688f

__device__ __forceinline__ unsigned short f2bf(float f) {
  union { float f; unsigned int u; } a;
  a.f = f;
  unsigned int u = a.u;
  return (unsigned short)((u + 0x7fffu + ((u >> 16) & 1u)) >> 16); // RNE
}

// packed f32x2 -> bf16x2 (v_cvt_pk_bf16_f32), low short = first arg
__device__ __forceinline__ unsigned int pkbf(float a, float b) {
  union { __hip_bfloat162 h; unsigned int u; } cv;
  cv.h = __float22bfloat162_rn(float2{a, b});
  return cv.u;
}

__device__ __forceinline__ float fast_exp2(float x) {
#if defined(__has_builtin) && __has_builtin(__builtin_amdgcn_exp2f)
  return __builtin_amdgcn_exp2f(x);
#else
  return exp2f(x);
#endif
}

// async global->LDS, 16B per lane. LDS dest is wave-uniform base + lane*16.
typedef const __attribute__((address_space(1))) void* gas1_t;
typedef __attribute__((address_space(3))) void* las3_t;
__device__ __forceinline__ void gload16(const void* g, void* l) {
  __builtin_amdgcn_global_load_lds((gas1_t)(unsigned long long)g,
                                   (las3_t)(unsigned int)(unsigned long long)l,
                                   16, 0, 0);
}

// ---------------------------------------------------------------------------
// Kernel 1 (fused): LayerNorm rows (blocks 0..4095) + weight bf16 cast
// (blocks 4096..8191).
// ---------------------------------------------------------------------------
__global__ __launch_bounds__(256) void ln_cast_kernel(const float* __restrict__ x,
                                                      const float* __restrict__ gamma,
                                                      const float* __restrict__ beta,
                                                      unsigned short* __restrict__ xn,
                                                      const float* __restrict__ w0,
                                                      const float* __restrict__ w1,
                                                      const float* __restrict__ w2,
                                                      const float* __restrict__ w3,
                                                      unsigned short* __restrict__ wdst) {
  const int t = threadIdx.x;
  if (blockIdx.x >= M_TOT) {
    const int cb = blockIdx.x - M_TOT;   // 0..4095
    const int y = cb >> 10;              // matrix index 0..3
    const float* s = (y == 0) ? w0 : (y == 1) ? w1 : (y == 2) ? w2 : w3;
    const int i = (cb & 1023) * 256 + t; // float4 index within matrix
    const float4 v = ((const float4*)s)[i];
    ushort4 o;
    o.x = f2bf(v.x);
    o.y = f2bf(v.y);
    o.z = f2bf(v.z);
    o.w = f2bf(v.w);
    ((ushort4*)(wdst + (size_t)y * H * H))[i] = o;
    return;
  }
  const int row = blockIdx.x;
  const float* xr = x + (size_t)row * H;
  float4 v = ((const float4*)xr)[t];
  float s = v.x + v.y + v.z + v.w;
  float s2 = v.x * v.x + v.y * v.y + v.z * v.z + v.w * v.w;
#pragma unroll
  for (int o = 32; o; o >>= 1) {
    s += __shfl_xor(s, o, 64);
    s2 += __shfl_xor(s2, o, 64);
  }
  __shared__ float red[8];
  const int wave = t >> 6;
  if ((t & 63) == 0) {
    red[wave] = s;
    red[wave + 4] = s2;
  }
  __syncthreads();
  const float ts = red[0] + red[1] + red[2] + red[3];
  const float ts2 = red[4] + red[5] + red[6] + red[7];
  const float mu = ts * (1.0f / (float)H);
  const float var = ts2 * (1.0f / (float)H) - mu * mu;
  const float rstd = rsqrtf(var + 1e-5f);
  const float4 g = ((const float4*)gamma)[t];
  const float4 b = ((const float4*)beta)[t];
  ushort4 o;
  o.x = f2bf((v.x - mu) * rstd * g.x + b.x);
  o.y = f2bf((v.y - mu) * rstd * g.y + b.y);
  o.z = f2bf((v.z - mu) * rstd * g.z + b.z);
  o.w = f2bf((v.w - mu) * rstd * g.w + b.w);
  ((ushort4*)(xn + (size_t)row * H))[t] = o;
}

// ---------------------------------------------------------------------------
// 128x128x(BK=32) bf16 MFMA GEMM (16x16x32, 32 KB LDS, double-buffered,
// one barrier per K-iter, 4 blocks/CU) with XCD-AWARE 1-D GRID:
//   xcd = id & 7; each XCD owns NPX consecutive N-blocks (W-slice stays in
//   its 4 MB L2); M-blocks iterate within the XCD.
// EPI=0 (NPX=3): QKV epilogue. Q cols (<1024) scaled by C2_SCALE.
//        cols<2048 -> qk natural; cols>=2048 -> V transposed vt[b][h*64+d][s].
// EPI=1 (NPX=1): proj epilogue -> fp32 out = acc + bo[col] + x (residual).
// ---------------------------------------------------------------------------
template <int EPI, int NPX>
__global__ __launch_bounds__(256, 4) void gemm128(const unsigned short* __restrict__ A,
                                                  const unsigned short* __restrict__ W,
                                                  unsigned short* __restrict__ qk,
                                                  unsigned short* __restrict__ vt,
                                                  const float* __restrict__ bo,
                                                  const float* __restrict__ x,
                                                  float* __restrict__ out) {
  const int id = blockIdx.x;
  const int xcd = id & 7;
  const int r = id >> 3;
  const int nb = xcd * NPX + (r % NPX);
  const int mb = r / NPX;
  const int m0 = mb * 128;
  const int n0 = nb * 128;
  const int tid = threadIdx.x;
  const int wave = tid >> 6;
  const int lane = tid & 63;
  const int l16 = lane & 15;
  const int quad = lane >> 4;
  const int wx = wave & 1, wy = wave >> 1;

  __shared__ __align__(16) unsigned short As[2][128 * 32];
  __shared__ __align__(16) unsigned short Bs[2][128 * 32];

  // staging: wave stages 32 rows (2 gload16 instrs per matrix)
  const int sub = lane >> 2;       // row within 16-row group
  const int kcol = (lane & 3) * 8; // 4 lanes cover 32 cols
  const unsigned short* ag = A + (size_t)(m0 + wave * 32 + sub) * H + kcol;
  const unsigned short* bg = W + (size_t)(n0 + wave * 32 + sub) * H + kcol;
  const int lofs = wave * 32 * 32;

  f32x4 acc[4][4] = {};

  // prologue: stage k0=0 into buffer 0
  gload16(ag, &As[0][lofs]);
  gload16(ag + 16 * H, &As[0][lofs + 16 * 32]);
  gload16(bg, &Bs[0][lofs]);
  gload16(bg + 16 * H, &Bs[0][lofs + 16 * 32]);

  for (int it = 0; it < H / 32; it++) {
    const int bi = it & 1;
    __syncthreads(); // drains buf[bi] loads (issued a full iter ago)
    if (it + 1 < H / 32) {
      const int k1 = (it + 1) * 32;
      gload16(ag + k1, &As[bi ^ 1][lofs]);
      gload16(ag + k1 + 16 * H, &As[bi ^ 1][lofs + 16 * 32]);
      gload16(bg + k1, &Bs[bi ^ 1][lofs]);
      gload16(bg + k1 + 16 * H, &Bs[bi ^ 1][lofs + 16 * 32]);
    }
    bf16x8 af[4], bf[4];
#pragma unroll
    for (int t = 0; t < 4; t++) {
      af[t] = *(const bf16x8*)&As[bi][(wy * 64 + t * 16 + l16) * 32 + quad * 8];
      bf[t] = *(const bf16x8*)&Bs[bi][(wx * 64 + t * 16 + l16) * 32 + quad * 8];
    }
#pragma unroll
    for (int i = 0; i < 4; i++)
#pragma unroll
      for (int j = 0; j < 4; j++)
        acc[i][j] = __builtin_amdgcn_mfma_f32_16x16x32_bf16(af[i], bf[j], acc[i][j], 0, 0, 0);
  }

  if (EPI == 0) {
#pragma unroll
    for (int j = 0; j < 4; j++) {
      const int cb = n0 + wx * 64 + j * 16; // wave-uniform tile col base
      if (cb < 2048) {
        const float qs = (cb < 1024) ? C2_SCALE : 1.0f;
#pragma unroll
        for (int i = 0; i < 4; i++) {
          const int row = m0 + wy * 64 + i * 16 + quad * 4;
#pragma unroll
          for (int r2 = 0; r2 < 4; r2++)
            qk[(size_t)(row + r2) * 2048 + cb + l16] = f2bf(acc[i][j][r2] * qs);
        }
      } else {
        const int n = cb + l16 - 2048; // h*64+d
#pragma unroll
        for (int i = 0; i < 4; i++) {
          const int row0 = m0 + wy * 64 + i * 16 + quad * 4;
          const int b = row0 >> 11;
          const int s = row0 & 2047;
          ushort4 p;
          p.x = f2bf(acc[i][j][0]);
          p.y = f2bf(acc[i][j][1]);
          p.z = f2bf(acc[i][j][2]);
          p.w = f2bf(acc[i][j][3]);
          *(ushort4*)&vt[((size_t)b * 1024 + n) * SEQ + s] = p;
        }
      }
    }
  } else {
#pragma unroll
    for (int j = 0; j < 4; j++) {
      const int col = n0 + wx * 64 + j * 16 + l16;
      const float bv = bo[col];
#pragma unroll
      for (int i = 0; i < 4; i++) {
        const int row = m0 + wy * 64 + i * 16 + quad * 4;
#pragma unroll
        for (int r2 = 0; r2 < 4; r2++) {
          const size_t idx = (size_t)(row + r2) * H + col;
          out[idx] = acc[i][j][r2] + bv + x[idx];
        }
      }
    }
  }
}

// ---------------------------------------------------------------------------
// Flash attention v8: v5 structure (32x32x16, in-register P, LDS-staged K/V,
// 512 blocks, 1 barrier/iter) + DEFERRED-PV PIPELINE (T15) + setprio (T5):
//   - V-frags of tile t are read into registers (vfP) during iter t, but
//     PV(t) is issued during iter t+1 right after QK(t+1)'s MFMAs, so the
//     matrix pipe crunches PV(t) underneath exp2(t+1)'s long trans chain
//     (the dominant serial block, ~256 cyc/wave-iter).
//   - PV consumes only registers (wP, vfP) -> immune to the LDS prefetch
//     overwriting buf[(t-1)&1] during iter t+1.
//   - setprio(1) around the merged QK+PV MFMA cluster.
// ---------------------------------------------------------------------------
__global__ __launch_bounds__(256, 2) void attn_kernel(const unsigned short* __restrict__ qk,
                                                      const unsigned short* __restrict__ vt,
                                                      unsigned short* __restrict__ O) {
  const int id = blockIdx.x; // 512 blocks
  const int xcd = id & 7;
  const int slot = id >> 3;       // 0..63
  const int qt = slot & 15;       // q-tile within (b,h)
  const int g = slot >> 4;        // 0..3
  const int combo = xcd * 4 + g;  // 0..31
  const int h = combo & 15;
  const int b = combo >> 4;
  const int tid = threadIdx.x;
  const int wave = tid >> 6;
  const int lane = tid & 63;
  const int l31 = lane & 31;
  const int l7 = lane & 7;
  const int hi = lane >> 5;

  __shared__ __align__(16) unsigned short Kt[2][64 * 64];
  __shared__ __align__(16) unsigned short Vt[2][64 * 64]; // [d][s]

  const unsigned short* Qbase = qk + (size_t)b * SEQ * 2048 + h * 64;
  const unsigned short* Kbase = qk + (size_t)b * SEQ * 2048 + 1024 + h * 64;
  const unsigned short* Vbase = vt + ((size_t)b * 1024 + h * 64) * SEQ;

  // staging geometry: one gload16 covers 8 rows x 64 shorts (1 KB), XOR swizzle
  const int rIn = lane >> 3;
  const int gsw = (lane & 7) ^ rIn;
  const int ch0 = 2 * wave;

  // Q fragments (B-operand, hoisted): B[n=l31 -> qrow][k=hi*8+e -> d in chunk kc]
  const int qrow = qt * 128 + wave * 32 + l31;
  bf16x8 aq[4];
#pragma unroll
  for (int kc = 0; kc < 4; kc++)
    aq[kc] = *(const bf16x8*)(Qbase + (size_t)qrow * 2048 + kc * 16 + hi * 8);

  f32x16 o_acc[2] = {}; // [dt] O^T: col=l31=qrow, row=(reg&3)+8*(reg>>2)+4*hi -> d
  float lc[4] = {};     // partial denominators (4 chains)

  // pipeline state: P words + V frags of the PREVIOUS tile
  unsigned int wP[2][8]; // [mt][gi]
  bf16x8 vfP[4][2];      // [sc][dt]

  // prologue: stage tile 0 into buffer 0
#pragma unroll
  for (int c = 0; c < 2; c++) {
    const int ch = ch0 + c;
    const int row = ch * 8 + rIn;
    gload16(Kbase + (size_t)row * 2048 + gsw * 8, &Kt[0][ch * 512]);
    gload16(Vbase + (size_t)row * SEQ + gsw * 8, &Vt[0][ch * 512]);
  }

  // ======== iter 0 (peeled): QK(0), exp2/pack(0) -> wP, vf(0) -> vfP ========
  {
    __syncthreads(); // buf0 loads done
    // prefetch tile 1 -> buf 1
#pragma unroll
    for (int c = 0; c < 2; c++) {
      const int ch = ch0 + c;
      const int row = ch * 8 + rIn;
      gload16(Kbase + (size_t)(64 + row) * 2048 + gsw * 8, &Kt[1][ch * 512]);
      gload16(Vbase + (size_t)row * SEQ + 64 + gsw * 8, &Vt[1][ch * 512]);
    }
    f32x16 s0 = {}, s1 = {};
    __builtin_amdgcn_s_setprio(1);
#pragma unroll
    for (int kc = 0; kc < 4; kc++) {
      const bf16x8 kf0 = *(const bf16x8*)&Kt[0][(l31)*64 + ((kc * 16 + hi * 8) ^ (l7 * 8))];
      const bf16x8 kf1 = *(const bf16x8*)&Kt[0][(32 + l31) * 64 + ((kc * 16 + hi * 8) ^ (l7 * 8))];
      s0 = __builtin_amdgcn_mfma_f32_32x32x16_bf16(kf0, aq[kc], s0, 0, 0, 0);
      s1 = __builtin_amdgcn_mfma_f32_32x32x16_bf16(kf1, aq[kc], s1, 0, 0, 0);
    }
    __builtin_amdgcn_s_setprio(0);
    {
      float p[16];
#pragma unroll
      for (int r2 = 0; r2 < 16; r2++) p[r2] = fast_exp2(s0[r2]);
      lc[0] += ((p[0] + p[1]) + (p[2] + p[3])) + ((p[8] + p[9]) + (p[10] + p[11]));
      lc[1] += ((p[4] + p[5]) + (p[6] + p[7])) + ((p[12] + p[13]) + (p[14] + p[15]));
#pragma unroll
      for (int gi = 0; gi < 8; gi++) wP[0][gi] = pkbf(p[2 * gi], p[2 * gi + 1]);
    }
    {
      float p[16];
#pragma unroll
      for (int r2 = 0; r2 < 16; r2++) p[r2] = fast_exp2(s1[r2]);
      lc[2] += ((p[0] + p[1]) + (p[2] + p[3])) + ((p[8] + p[9]) + (p[10] + p[11]));
      lc[3] += ((p[4] + p[5]) + (p[6] + p[7])) + ((p[12] + p[13]) + (p[14] + p[15]));
#pragma unroll
      for (int gi = 0; gi < 8; gi++) wP[1][gi] = pkbf(p[2 * gi], p[2 * gi + 1]);
    }
#pragma unroll
    for (int sc = 0; sc < 4; sc++) {
      vfP[sc][0] = *(const bf16x8*)&Vt[0][(l31)*64 + ((sc * 16 + hi * 8) ^ (l7 * 8))];
      vfP[sc][1] = *(const bf16x8*)&Vt[0][(32 + l31) * 64 + ((sc * 16 + hi * 8) ^ (l7 * 8))];
    }
  }

  // ======== main loop: iter it does QK(it) + PV(it-1) + exp2/pack(it) ========
  for (int it = 1; it < SEQ / 64; it++) {
    const int bi = it & 1;
    __syncthreads(); // buf[bi] loads done; all waves done reading buf[bi^1]
    if (it + 1 < SEQ / 64) {
#pragma unroll
      for (int c = 0; c < 2; c++) {
        const int ch = ch0 + c;
        const int row = ch * 8 + rIn;
        gload16(Kbase + (size_t)((it + 1) * 64 + row) * 2048 + gsw * 8,
                &Kt[bi ^ 1][ch * 512]);
        gload16(Vbase + (size_t)row * SEQ + (it + 1) * 64 + gsw * 8,
                &Vt[bi ^ 1][ch * 512]);
      }
    }

    // QK(it): S^T = K (A) @ Q^T (B)
    f32x16 s0 = {}, s1 = {};
    __builtin_amdgcn_s_setprio(1);
#pragma unroll
    for (int kc = 0; kc < 4; kc++) {
      const bf16x8 kf0 = *(const bf16x8*)&Kt[bi][(l31)*64 + ((kc * 16 + hi * 8) ^ (l7 * 8))];
      const bf16x8 kf1 = *(const bf16x8*)&Kt[bi][(32 + l31) * 64 + ((kc * 16 + hi * 8) ^ (l7 * 8))];
      s0 = __builtin_amdgcn_mfma_f32_32x32x16_bf16(kf0, aq[kc], s0, 0, 0, 0);
      s1 = __builtin_amdgcn_mfma_f32_32x32x16_bf16(kf1, aq[kc], s1, 0, 0, 0);
    }

    // PV(it-1): O^T += V^T (A) @ P^T (B) — registers only (wP, vfP).
    // Issued now so the matrix pipe works underneath exp2(it)'s trans chain.
#pragma unroll
    for (int sc = 0; sc < 4; sc++) {
      const int n0i = 2 * sc, n1i = 2 * sc + 1;
      const int mt0 = n0i >> 2, b0 = n0i & 3;
      const int mt1 = n1i >> 2, b1 = n1i & 3;
      const auto rA = __builtin_amdgcn_permlane32_swap(wP[mt0][2 * b0], wP[mt1][2 * b1],
                                                       false, false);
      const auto rB = __builtin_amdgcn_permlane32_swap(wP[mt0][2 * b0 + 1], wP[mt1][2 * b1 + 1],
                                                       false, false);
      union { unsigned int u[4]; bf16x8 v; } pb;
      pb.u[0] = rA[0]; // k = sc*16+hi*8 + {0,1}
      pb.u[1] = rB[0]; // + {2,3}
      pb.u[2] = rA[1]; // + {4,5}
      pb.u[3] = rB[1]; // + {6,7}
      o_acc[0] = __builtin_amdgcn_mfma_f32_32x32x16_bf16(vfP[sc][0], pb.v, o_acc[0], 0, 0, 0);
      o_acc[1] = __builtin_amdgcn_mfma_f32_32x32x16_bf16(vfP[sc][1], pb.v, o_acc[1], 0, 0, 0);
    }
    __builtin_amdgcn_s_setprio(0);

    // exp2/pack(it) -> wP (overlaps PV(it-1) in the matrix pipe)
    {
      float p[16];
#pragma unroll
      for (int r2 = 0; r2 < 16; r2++) p[r2] = fast_exp2(s0[r2]);
      lc[0] += ((p[0] + p[1]) + (p[2] + p[3])) + ((p[8] + p[9]) + (p[10] + p[11]));
      lc[1] += ((p[4] + p[5]) + (p[6] + p[7])) + ((p[12] + p[13]) + (p[14] + p[15]));
#pragma unroll
      for (int gi = 0; gi < 8; gi++) wP[0][gi] = pkbf(p[2 * gi], p[2 * gi + 1]);
    }
    {
      float p[16];
#pragma unroll
      for (int r2 = 0; r2 < 16; r2++) p[r2] = fast_exp2(s1[r2]);
      lc[2] += ((p[0] + p[1]) + (p[2] + p[3])) + ((p[8] + p[9]) + (p[10] + p[11]));
      lc[3] += ((p[4] + p[5]) + (p[6] + p[7])) + ((p[12] + p[13]) + (p[14] + p[15]));
#pragma unroll
      for (int gi = 0; gi < 8; gi++) wP[1][gi] = pkbf(p[2 * gi], p[2 * gi + 1]);
    }

    // vf(it) -> vfP registers (read before buf[bi] is overwritten at it+2)
#pragma unroll
    for (int sc = 0; sc < 4; sc++) {
      vfP[sc][0] = *(const bf16x8*)&Vt[bi][(l31)*64 + ((sc * 16 + hi * 8) ^ (l7 * 8))];
      vfP[sc][1] = *(const bf16x8*)&Vt[bi][(32 + l31) * 64 + ((sc * 16 + hi * 8) ^ (l7 * 8))];
    }
  }

  // ======== drain: PV(last) ========
  __builtin_amdgcn_s_setprio(1);
#pragma unroll
  for (int sc = 0; sc < 4; sc++) {
    const int n0i = 2 * sc, n1i = 2 * sc + 1;
    const int mt0 = n0i >> 2, b0 = n0i & 3;
    const int mt1 = n1i >> 2, b1 = n1i & 3;
    const auto rA = __builtin_amdgcn_permlane32_swap(wP[mt0][2 * b0], wP[mt1][2 * b1],
                                                     false, false);
    const auto rB = __builtin_amdgcn_permlane32_swap(wP[mt0][2 * b0 + 1], wP[mt1][2 * b1 + 1],
                                                     false, false);
    union { unsigned int u[4]; bf16x8 v; } pb;
    pb.u[0] = rA[0];
    pb.u[1] = rB[0];
    pb.u[2] = rA[1];
    pb.u[3] = rB[1];
    o_acc[0] = __builtin_amdgcn_mfma_f32_32x32x16_bf16(vfP[sc][0], pb.v, o_acc[0], 0, 0, 0);
    o_acc[1] = __builtin_amdgcn_mfma_f32_32x32x16_bf16(vfP[sc][1], pb.v, o_acc[1], 0, 0, 0);
  }
  __builtin_amdgcn_s_setprio(0);

  // epilogue: lanes l and l|32 hold complementary s-subsets of the same qrow
  float lsum = (lc[0] + lc[1]) + (lc[2] + lc[3]);
  const float l_i = lsum + __shfl_xor(lsum, 32, 64);
  const float inv = 1.0f / l_i;
  unsigned short* orow = O + ((size_t)(b * SEQ + qrow)) * H + h * 64;
#pragma unroll
  for (int dt = 0; dt < 2; dt++)
#pragma unroll
    for (int rg = 0; rg < 4; rg++) {
      uint2 d;
      d.x = pkbf(o_acc[dt][4 * rg + 0] * inv, o_acc[dt][4 * rg + 1] * inv);
      d.y = pkbf(o_acc[dt][4 * rg + 2] * inv, o_acc[dt][4 * rg + 3] * inv);
      *(uint2*)&orow[dt * 32 + 8 * rg + 4 * hi] = d;
    }
}

// ---------------------------------------------------------------------------
extern "C" void kernel_launch(void* const* d_in, const int* in_sizes, int n_in,
                              void* d_out, int out_size, void* d_ws, size_t ws_size,
                              hipStream_t stream) {
  const float* x = (const float*)d_in[0];
  const float* Wq = (const float*)d_in[1];
  const float* Wk = (const float*)d_in[2];
  const float* Wv = (const float*)d_in[3];
  const float* Wo = (const float*)d_in[4];
  const float* bo = (const float*)d_in[5];
  const float* gamma = (const float*)d_in[6];
  const float* beta = (const float*)d_in[7];
  float* out = (float*)d_out;

  unsigned short* ws = (unsigned short*)d_ws;
  unsigned short* xn = ws;                              // 4096*1024
  unsigned short* wcat = xn + (size_t)M_TOT * H;        // 4*1024*1024 (Wq,Wk,Wv,Wo)
  unsigned short* wob = wcat + (size_t)3 * H * H;
  unsigned short* qkb = wcat + (size_t)4 * H * H;       // 4096*2048 (Q | K)
  unsigned short* vtb = qkb + (size_t)M_TOT * 2048;     // 2*1024*2048 (V^T)
  unsigned short* atb = vtb + (size_t)BATCH * H * SEQ;  // 4096*1024

  ln_cast_kernel<<<M_TOT + 4096, 256, 0, stream>>>(x, gamma, beta, xn, Wq, Wk, Wv, Wo,
                                                   wcat);
  // QKV: 32 M-blocks x 24 N-blocks, XCD-supertiled (3 N-blocks per XCD)
  gemm128<0, 3><<<(M_TOT / 128) * (NQKV / 128), 256, 0, stream>>>(
      xn, wcat, qkb, vtb, nullptr, nullptr, nullptr);
  // attn: 512 blocks (128-row q-tiles), XCD-supertiled (4 (b,h) combos per XCD)
  attn_kernel<<<(SEQ / 128) * NHEAD * BATCH, 256, 0, stream>>>(qkb, vtb, atb);
  // proj: 32 M-blocks x 8 N-blocks, XCD-supertiled (1 N-block per XCD)
  gemm128<1, 1><<<(M_TOT / 128) * (H / 128), 256, 0, stream>>>(
      atb, wob, nullptr, nullptr, bo, x, out);
}

// Round 5
// 188.465 us; speedup vs baseline: 1.4116x; 1.0304x over previous
//
#include <hip/hip_runtime.h>
#include <hip/hip_bf16.h>

// Problem constants
#define H 1024
#define NHEAD 16
#define HDIM 64
#define SEQ 2048
#define BATCH 2
#define M_TOT (BATCH * SEQ) // 4096 tokens
#define NQKV 3072           // fused QKV output cols

typedef __attribute__((ext_vector_type(8))) short bf16x8;  // 8 bf16 = 4 VGPRs (MFMA A/B frag)
typedef __attribute__((ext_vector_type(4))) float f32x4;   // 16x16 MFMA C/D frag
typedef __attribute__((ext_vector_type(16))) float f32x16; // 32x32 MFMA C/D frag

// (1/sqrt(HDIM)) * log2(e), folded into Q at the QKV-GEMM epilogue
#define C2_SCALE 0.18033688f

__device__ __forceinline__ unsigned short f2bf(float f) {
  union { float f; unsigned int u; } a;
  a.f = f;
  unsigned int u = a.u;
  return (unsigned short)((u + 0x7fffu + ((u >> 16) & 1u)) >> 16); // RNE
}

// packed f32x2 -> bf16x2 (v_cvt_pk_bf16_f32), low short = first arg
__device__ __forceinline__ unsigned int pkbf(float a, float b) {
  union { __hip_bfloat162 h; unsigned int u; } cv;
  cv.h = __float22bfloat162_rn(float2{a, b});
  return cv.u;
}

__device__ __forceinline__ float fast_exp2(float x) {
#if defined(__has_builtin) && __has_builtin(__builtin_amdgcn_exp2f)
  return __builtin_amdgcn_exp2f(x);
#else
  return exp2f(x);
#endif
}

// async global->LDS, 16B per lane. LDS dest is wave-uniform base + lane*16.
typedef const __attribute__((address_space(1))) void* gas1_t;
typedef __attribute__((address_space(3))) void* las3_t;
__device__ __forceinline__ void gload16(const void* g, void* l) {
  __builtin_amdgcn_global_load_lds((gas1_t)(unsigned long long)g,
                                   (las3_t)(unsigned int)(unsigned long long)l,
                                   16, 0, 0);
}

// ---------------------------------------------------------------------------
// Kernel 1 (fused): LayerNorm rows (blocks 0..4095) + weight bf16 cast
// (blocks 4096..8191).
// ---------------------------------------------------------------------------
__global__ __launch_bounds__(256) void ln_cast_kernel(const float* __restrict__ x,
                                                      const float* __restrict__ gamma,
                                                      const float* __restrict__ beta,
                                                      unsigned short* __restrict__ xn,
                                                      const float* __restrict__ w0,
                                                      const float* __restrict__ w1,
                                                      const float* __restrict__ w2,
                                                      const float* __restrict__ w3,
                                                      unsigned short* __restrict__ wdst) {
  const int t = threadIdx.x;
  if (blockIdx.x >= M_TOT) {
    const int cb = blockIdx.x - M_TOT;   // 0..4095
    const int y = cb >> 10;              // matrix index 0..3
    const float* s = (y == 0) ? w0 : (y == 1) ? w1 : (y == 2) ? w2 : w3;
    const int i = (cb & 1023) * 256 + t; // float4 index within matrix
    const float4 v = ((const float4*)s)[i];
    ushort4 o;
    o.x = f2bf(v.x);
    o.y = f2bf(v.y);
    o.z = f2bf(v.z);
    o.w = f2bf(v.w);
    ((ushort4*)(wdst + (size_t)y * H * H))[i] = o;
    return;
  }
  const int row = blockIdx.x;
  const float* xr = x + (size_t)row * H;
  float4 v = ((const float4*)xr)[t];
  float s = v.x + v.y + v.z + v.w;
  float s2 = v.x * v.x + v.y * v.y + v.z * v.z + v.w * v.w;
#pragma unroll
  for (int o = 32; o; o >>= 1) {
    s += __shfl_xor(s, o, 64);
    s2 += __shfl_xor(s2, o, 64);
  }
  __shared__ float red[8];
  const int wave = t >> 6;
  if ((t & 63) == 0) {
    red[wave] = s;
    red[wave + 4] = s2;
  }
  __syncthreads();
  const float ts = red[0] + red[1] + red[2] + red[3];
  const float ts2 = red[4] + red[5] + red[6] + red[7];
  const float mu = ts * (1.0f / (float)H);
  const float var = ts2 * (1.0f / (float)H) - mu * mu;
  const float rstd = rsqrtf(var + 1e-5f);
  const float4 g = ((const float4*)gamma)[t];
  const float4 b = ((const float4*)beta)[t];
  ushort4 o;
  o.x = f2bf((v.x - mu) * rstd * g.x + b.x);
  o.y = f2bf((v.y - mu) * rstd * g.y + b.y);
  o.z = f2bf((v.z - mu) * rstd * g.z + b.z);
  o.w = f2bf((v.w - mu) * rstd * g.w + b.w);
  ((ushort4*)(xn + (size_t)row * H))[t] = o;
}

// ---------------------------------------------------------------------------
// 128x128x(BK=32) bf16 MFMA GEMM (16x16x32, 32 KB LDS, double-buffered,
// one barrier per K-iter, 4 blocks/CU) with XCD-AWARE 1-D GRID. Used for the
// QKV GEMM (EPI=0, NPX=3): Q cols (<1024) scaled by C2_SCALE; cols<2048 ->
// qk natural; cols>=2048 -> V transposed vt[b][h*64+d][s].
// ---------------------------------------------------------------------------
template <int EPI, int NPX>
__global__ __launch_bounds__(256, 4) void gemm128(const unsigned short* __restrict__ A,
                                                  const unsigned short* __restrict__ W,
                                                  unsigned short* __restrict__ qk,
                                                  unsigned short* __restrict__ vt,
                                                  const float* __restrict__ bo,
                                                  const float* __restrict__ x,
                                                  float* __restrict__ out) {
  const int id = blockIdx.x;
  const int xcd = id & 7;
  const int r = id >> 3;
  const int nb = xcd * NPX + (r % NPX);
  const int mb = r / NPX;
  const int m0 = mb * 128;
  const int n0 = nb * 128;
  const int tid = threadIdx.x;
  const int wave = tid >> 6;
  const int lane = tid & 63;
  const int l16 = lane & 15;
  const int quad = lane >> 4;
  const int wx = wave & 1, wy = wave >> 1;

  __shared__ __align__(16) unsigned short As[2][128 * 32];
  __shared__ __align__(16) unsigned short Bs[2][128 * 32];

  // staging: wave stages 32 rows (2 gload16 instrs per matrix)
  const int sub = lane >> 2;       // row within 16-row group
  const int kcol = (lane & 3) * 8; // 4 lanes cover 32 cols
  const unsigned short* ag = A + (size_t)(m0 + wave * 32 + sub) * H + kcol;
  const unsigned short* bg = W + (size_t)(n0 + wave * 32 + sub) * H + kcol;
  const int lofs = wave * 32 * 32;

  f32x4 acc[4][4] = {};

  // prologue: stage k0=0 into buffer 0
  gload16(ag, &As[0][lofs]);
  gload16(ag + 16 * H, &As[0][lofs + 16 * 32]);
  gload16(bg, &Bs[0][lofs]);
  gload16(bg + 16 * H, &Bs[0][lofs + 16 * 32]);

  for (int it = 0; it < H / 32; it++) {
    const int bi = it & 1;
    __syncthreads(); // drains buf[bi] loads (issued a full iter ago)
    if (it + 1 < H / 32) {
      const int k1 = (it + 1) * 32;
      gload16(ag + k1, &As[bi ^ 1][lofs]);
      gload16(ag + k1 + 16 * H, &As[bi ^ 1][lofs + 16 * 32]);
      gload16(bg + k1, &Bs[bi ^ 1][lofs]);
      gload16(bg + k1 + 16 * H, &Bs[bi ^ 1][lofs + 16 * 32]);
    }
    bf16x8 af[4], bf[4];
#pragma unroll
    for (int t = 0; t < 4; t++) {
      af[t] = *(const bf16x8*)&As[bi][(wy * 64 + t * 16 + l16) * 32 + quad * 8];
      bf[t] = *(const bf16x8*)&Bs[bi][(wx * 64 + t * 16 + l16) * 32 + quad * 8];
    }
#pragma unroll
    for (int i = 0; i < 4; i++)
#pragma unroll
      for (int j = 0; j < 4; j++)
        acc[i][j] = __builtin_amdgcn_mfma_f32_16x16x32_bf16(af[i], bf[j], acc[i][j], 0, 0, 0);
  }

  if (EPI == 0) {
#pragma unroll
    for (int j = 0; j < 4; j++) {
      const int cb = n0 + wx * 64 + j * 16; // wave-uniform tile col base
      if (cb < 2048) {
        const float qs = (cb < 1024) ? C2_SCALE : 1.0f;
#pragma unroll
        for (int i = 0; i < 4; i++) {
          const int row = m0 + wy * 64 + i * 16 + quad * 4;
#pragma unroll
          for (int r2 = 0; r2 < 4; r2++)
            qk[(size_t)(row + r2) * 2048 + cb + l16] = f2bf(acc[i][j][r2] * qs);
        }
      } else {
        const int n = cb + l16 - 2048; // h*64+d
#pragma unroll
        for (int i = 0; i < 4; i++) {
          const int row0 = m0 + wy * 64 + i * 16 + quad * 4;
          const int b = row0 >> 11;
          const int s = row0 & 2047;
          ushort4 p;
          p.x = f2bf(acc[i][j][0]);
          p.y = f2bf(acc[i][j][1]);
          p.z = f2bf(acc[i][j][2]);
          p.w = f2bf(acc[i][j][3]);
          *(ushort4*)&vt[((size_t)b * 1024 + n) * SEQ + s] = p;
        }
      }
    }
  } else {
#pragma unroll
    for (int j = 0; j < 4; j++) {
      const int col = n0 + wx * 64 + j * 16 + l16;
      const float bv = bo[col];
#pragma unroll
      for (int i = 0; i < 4; i++) {
        const int row = m0 + wy * 64 + i * 16 + quad * 4;
#pragma unroll
        for (int r2 = 0; r2 < 4; r2++) {
          const size_t idx = (size_t)(row + r2) * H + col;
          out[idx] = acc[i][j][r2] + bv + x[idx];
        }
      }
    }
  }
}

// ---------------------------------------------------------------------------
// Proj GEMM: 64x128x(BK=32) tiles -> grid 512 blocks = 2 blocks/CU (the
// 128x128 version gave only 256 blocks = 1 block/CU, exposing every barrier
// drain; m114: the m97-structure needs >=2 co-resident blocks for implicit
// MFMA/staging overlap). LDS 24 KB. Epilogue: out = acc + bo[col] + x.
// Grid: id&7 = N-block (== XCD, Wo 128-col slice L2-resident), id>>3 = M-block.
// ---------------------------------------------------------------------------
__global__ __launch_bounds__(256, 4) void proj64(const unsigned short* __restrict__ A,
                                                 const unsigned short* __restrict__ W,
                                                 const float* __restrict__ bo,
                                                 const float* __restrict__ x,
                                                 float* __restrict__ out) {
  const int id = blockIdx.x; // 512 blocks
  const int nb = id & 7;     // N-block = XCD
  const int mb = id >> 3;    // 0..63
  const int m0 = mb * 64;
  const int n0 = nb * 128;
  const int tid = threadIdx.x;
  const int wave = tid >> 6;
  const int lane = tid & 63;
  const int l16 = lane & 15;
  const int quad = lane >> 4;
  const int wx = wave & 1, wy = wave >> 1;

  __shared__ __align__(16) unsigned short As[2][64 * 32];
  __shared__ __align__(16) unsigned short Bs[2][128 * 32];

  // staging: wave stages 16 A-rows (1 gload16) + 32 B-rows (2 gload16)
  const int sub = lane >> 2;       // row within 16-row group
  const int kcol = (lane & 3) * 8; // 4 lanes cover 32 cols
  const unsigned short* ag = A + (size_t)(m0 + wave * 16 + sub) * H + kcol;
  const unsigned short* bg = W + (size_t)(n0 + wave * 32 + sub) * H + kcol;
  const int lofsA = wave * 16 * 32;
  const int lofsB = wave * 32 * 32;

  f32x4 acc[2][4] = {};

  // prologue: stage k0=0 into buffer 0
  gload16(ag, &As[0][lofsA]);
  gload16(bg, &Bs[0][lofsB]);
  gload16(bg + 16 * H, &Bs[0][lofsB + 16 * 32]);

  for (int it = 0; it < H / 32; it++) {
    const int bi = it & 1;
    __syncthreads(); // drains buf[bi] loads (issued a full iter ago)
    if (it + 1 < H / 32) {
      const int k1 = (it + 1) * 32;
      gload16(ag + k1, &As[bi ^ 1][lofsA]);
      gload16(bg + k1, &Bs[bi ^ 1][lofsB]);
      gload16(bg + k1 + 16 * H, &Bs[bi ^ 1][lofsB + 16 * 32]);
    }
    bf16x8 af[2], bf[4];
#pragma unroll
    for (int t = 0; t < 2; t++)
      af[t] = *(const bf16x8*)&As[bi][(wy * 32 + t * 16 + l16) * 32 + quad * 8];
#pragma unroll
    for (int t = 0; t < 4; t++)
      bf[t] = *(const bf16x8*)&Bs[bi][(wx * 64 + t * 16 + l16) * 32 + quad * 8];
#pragma unroll
    for (int i = 0; i < 2; i++)
#pragma unroll
      for (int j = 0; j < 4; j++)
        acc[i][j] = __builtin_amdgcn_mfma_f32_16x16x32_bf16(af[i], bf[j], acc[i][j], 0, 0, 0);
  }

#pragma unroll
  for (int j = 0; j < 4; j++) {
    const int col = n0 + wx * 64 + j * 16 + l16;
    const float bv = bo[col];
#pragma unroll
    for (int i = 0; i < 2; i++) {
      const int row = m0 + wy * 32 + i * 16 + quad * 4;
#pragma unroll
      for (int r2 = 0; r2 < 4; r2++) {
        const size_t idx = (size_t)(row + r2) * H + col;
        out[idx] = acc[i][j][r2] + bv + x[idx];
      }
    }
  }
}

// ---------------------------------------------------------------------------
// Flash attention v5 (best measured: 48.4 us): 32x32x16 MFMA formulation with
// FULLY IN-REGISTER P (cvt_pk + permlane32_swap), LDS-staged double-buffered
// K/V, 1 barrier/iter, 512 blocks XCD-supertiled.
// ---------------------------------------------------------------------------
__global__ __launch_bounds__(256, 2) void attn_kernel(const unsigned short* __restrict__ qk,
                                                      const unsigned short* __restrict__ vt,
                                                      unsigned short* __restrict__ O) {
  const int id = blockIdx.x; // 512 blocks
  const int xcd = id & 7;
  const int slot = id >> 3;       // 0..63
  const int qt = slot & 15;       // q-tile within (b,h)
  const int g = slot >> 4;        // 0..3
  const int combo = xcd * 4 + g;  // 0..31
  const int h = combo & 15;
  const int b = combo >> 4;
  const int tid = threadIdx.x;
  const int wave = tid >> 6;
  const int lane = tid & 63;
  const int l31 = lane & 31;
  const int l7 = lane & 7;
  const int hi = lane >> 5;

  __shared__ __align__(16) unsigned short Kt[2][64 * 64];
  __shared__ __align__(16) unsigned short Vt[2][64 * 64]; // [d][s]

  const unsigned short* Qbase = qk + (size_t)b * SEQ * 2048 + h * 64;
  const unsigned short* Kbase = qk + (size_t)b * SEQ * 2048 + 1024 + h * 64;
  const unsigned short* Vbase = vt + ((size_t)b * 1024 + h * 64) * SEQ;

  // staging geometry: one gload16 covers 8 rows x 64 shorts (1 KB), XOR swizzle
  const int rIn = lane >> 3;
  const int gsw = (lane & 7) ^ rIn;
  const int ch0 = 2 * wave;

  // Q fragments (B-operand, hoisted): B[n=l31 -> qrow][k=hi*8+e -> d in chunk kc]
  const int qrow = qt * 128 + wave * 32 + l31;
  bf16x8 aq[4];
#pragma unroll
  for (int kc = 0; kc < 4; kc++)
    aq[kc] = *(const bf16x8*)(Qbase + (size_t)qrow * 2048 + kc * 16 + hi * 8);

  f32x16 o_acc[2] = {}; // [dt] O^T: col=l31=qrow, row=(reg&3)+8*(reg>>2)+4*hi -> d
  float lc[4] = {};     // partial denominators (4 chains)

  // prologue: stage tile 0 into buffer 0
#pragma unroll
  for (int c = 0; c < 2; c++) {
    const int ch = ch0 + c;
    const int row = ch * 8 + rIn;
    gload16(Kbase + (size_t)row * 2048 + gsw * 8, &Kt[0][ch * 512]);
    gload16(Vbase + (size_t)row * SEQ + gsw * 8, &Vt[0][ch * 512]);
  }

#pragma unroll 2
  for (int it = 0; it < SEQ / 64; it++) {
    const int bi = it & 1;
    __syncthreads(); // waits cur-buffer loads (vmcnt) + prev iter readers done
    if (it + 1 < SEQ / 64) {
#pragma unroll
      for (int c = 0; c < 2; c++) {
        const int ch = ch0 + c;
        const int row = ch * 8 + rIn;
        gload16(Kbase + (size_t)((it + 1) * 64 + row) * 2048 + gsw * 8,
                &Kt[bi ^ 1][ch * 512]);
        gload16(Vbase + (size_t)row * SEQ + (it + 1) * 64 + gsw * 8,
                &Vt[bi ^ 1][ch * 512]);
      }
    }

    // S^T = K (A) @ Q^T (B): 2 m-tiles (s 0..31 / 32..63) x 4 k-chunks
    f32x16 s_acc[2] = {};
#pragma unroll
    for (int kc = 0; kc < 4; kc++) {
#pragma unroll
      for (int mt = 0; mt < 2; mt++) {
        const bf16x8 kf = *(const bf16x8*)&Kt[bi][(mt * 32 + l31) * 64 +
                                                 ((kc * 16 + hi * 8) ^ (l7 * 8))];
        s_acc[mt] = __builtin_amdgcn_mfma_f32_32x32x16_bf16(kf, aq[kc], s_acc[mt], 0, 0, 0);
      }
    }

    // fixed-max softmax: p = exp2(s), all for qrow = l31; pack to bf16 pairs.
    // w[mt][g] covers s = 32*mt + {0,1}/{2,3} + 8*(g>>1) + 4*hi  (g even/odd)
    unsigned int w[2][8];
#pragma unroll
    for (int mt = 0; mt < 2; mt++) {
      float p[16];
#pragma unroll
      for (int r2 = 0; r2 < 16; r2++) p[r2] = fast_exp2(s_acc[mt][r2]);
      const float a0 = (p[0] + p[1]) + (p[2] + p[3]);
      const float a1 = (p[4] + p[5]) + (p[6] + p[7]);
      const float a2 = (p[8] + p[9]) + (p[10] + p[11]);
      const float a3 = (p[12] + p[13]) + (p[14] + p[15]);
      lc[mt * 2 + 0] += a0 + a2;
      lc[mt * 2 + 1] += a1 + a3;
#pragma unroll
      for (int gi = 0; gi < 8; gi++) w[mt][gi] = pkbf(p[2 * gi], p[2 * gi + 1]);
    }

    // O^T += V^T (A) @ P^T (B). Per s-chunk sc: two permlane32_swap calls
    // exchange the hi/lo half-wave words; B-frag = {rA.x, rB.x, rA.y, rB.y}.
#pragma unroll
    for (int sc = 0; sc < 4; sc++) {
      const int n0i = 2 * sc, n1i = 2 * sc + 1;
      const int mt0 = n0i >> 2, b0 = n0i & 3;
      const int mt1 = n1i >> 2, b1 = n1i & 3;
      const auto rA = __builtin_amdgcn_permlane32_swap(w[mt0][2 * b0], w[mt1][2 * b1],
                                                       false, false);
      const auto rB = __builtin_amdgcn_permlane32_swap(w[mt0][2 * b0 + 1], w[mt1][2 * b1 + 1],
                                                       false, false);
      union { unsigned int u[4]; bf16x8 v; } pb;
      pb.u[0] = rA[0]; // k = sc*16+hi*8 + {0,1}
      pb.u[1] = rB[0]; // + {2,3}
      pb.u[2] = rA[1]; // + {4,5}
      pb.u[3] = rB[1]; // + {6,7}
#pragma unroll
      for (int dt = 0; dt < 2; dt++) {
        const bf16x8 vf = *(const bf16x8*)&Vt[bi][(dt * 32 + l31) * 64 +
                                                  ((sc * 16 + hi * 8) ^ (l7 * 8))];
        o_acc[dt] = __builtin_amdgcn_mfma_f32_32x32x16_bf16(vf, pb.v, o_acc[dt], 0, 0, 0);
      }
    }
  }

  // epilogue: lanes l and l|32 hold complementary s-halves of the same qrow
  float lsum = (lc[0] + lc[1]) + (lc[2] + lc[3]);
  const float l_i = lsum + __shfl_xor(lsum, 32, 64);
  const float inv = 1.0f / l_i;
  unsigned short* orow = O + ((size_t)(b * SEQ + qrow)) * H + h * 64;
#pragma unroll
  for (int dt = 0; dt < 2; dt++)
#pragma unroll
    for (int rg = 0; rg < 4; rg++) {
      uint2 d;
      d.x = pkbf(o_acc[dt][4 * rg + 0] * inv, o_acc[dt][4 * rg + 1] * inv);
      d.y = pkbf(o_acc[dt][4 * rg + 2] * inv, o_acc[dt][4 * rg + 3] * inv);
      *(uint2*)&orow[dt * 32 + 8 * rg + 4 * hi] = d;
    }
}

// ---------------------------------------------------------------------------
extern "C" void kernel_launch(void* const* d_in, const int* in_sizes, int n_in,
                              void* d_out, int out_size, void* d_ws, size_t ws_size,
                              hipStream_t stream) {
  const float* x = (const float*)d_in[0];
  const float* Wq = (const float*)d_in[1];
  const float* Wk = (const float*)d_in[2];
  const float* Wv = (const float*)d_in[3];
  const float* Wo = (const float*)d_in[4];
  const float* bo = (const float*)d_in[5];
  const float* gamma = (const float*)d_in[6];
  const float* beta = (const float*)d_in[7];
  float* out = (float*)d_out;

  unsigned short* ws = (unsigned short*)d_ws;
  unsigned short* xn = ws;                              // 4096*1024
  unsigned short* wcat = xn + (size_t)M_TOT * H;        // 4*1024*1024 (Wq,Wk,Wv,Wo)
  unsigned short* wob = wcat + (size_t)3 * H * H;
  unsigned short* qkb = wcat + (size_t)4 * H * H;       // 4096*2048 (Q | K)
  unsigned short* vtb = qkb + (size_t)M_TOT * 2048;     // 2*1024*2048 (V^T)
  unsigned short* atb = vtb + (size_t)BATCH * H * SEQ;  // 4096*1024

  ln_cast_kernel<<<M_TOT + 4096, 256, 0, stream>>>(x, gamma, beta, xn, Wq, Wk, Wv, Wo,
                                                   wcat);
  // QKV: 32 M-blocks x 24 N-blocks, XCD-supertiled (3 N-blocks per XCD)
  gemm128<0, 3><<<(M_TOT / 128) * (NQKV / 128), 256, 0, stream>>>(
      xn, wcat, qkb, vtb, nullptr, nullptr, nullptr);
  // attn: 512 blocks (128-row q-tiles), XCD-supertiled (4 (b,h) combos per XCD)
  attn_kernel<<<(SEQ / 128) * NHEAD * BATCH, 256, 0, stream>>>(qkb, vtb, atb);
  // proj: 64 M-blocks x 8 N-blocks = 512 blocks (2 blocks/CU)
  proj64<<<(M_TOT / 64) * (H / 128), 256, 0, stream>>>(atb, wob, bo, x, out);
}

// Round 6
// 186.674 us; speedup vs baseline: 1.4252x; 1.0096x over previous
//
#include <hip/hip_runtime.h>
#include <hip/hip_bf16.h>

// Problem constants
#define H 1024
#define NHEAD 16
#define HDIM 64
#define SEQ 2048
#define BATCH 2
#define M_TOT (BATCH * SEQ) // 4096 tokens
#define NQKV 3072           // fused QKV output cols

typedef __attribute__((ext_vector_type(8))) short bf16x8;  // 8 bf16 = 4 VGPRs (MFMA A/B frag)
typedef __attribute__((ext_vector_type(4))) float f32x4;   // 16x16 MFMA C/D frag
typedef __attribute__((ext_vector_type(16))) float f32x16; // 32x32 MFMA C/D frag

// (1/sqrt(HDIM)) * log2(e), folded into Q at the QKV-GEMM epilogue
#define C2_SCALE 0.18033688f

__device__ __forceinline__ unsigned short f2bf(float f) {
  union { float f; unsigned int u; } a;
  a.f = f;
  unsigned int u = a.u;
  return (unsigned short)((u + 0x7fffu + ((u >> 16) & 1u)) >> 16); // RNE
}

// packed f32x2 -> bf16x2 (v_cvt_pk_bf16_f32), low short = first arg
__device__ __forceinline__ unsigned int pkbf(float a, float b) {
  union { __hip_bfloat162 h; unsigned int u; } cv;
  cv.h = __float22bfloat162_rn(float2{a, b});
  return cv.u;
}

__device__ __forceinline__ float fast_exp2(float x) {
#if defined(__has_builtin) && __has_builtin(__builtin_amdgcn_exp2f)
  return __builtin_amdgcn_exp2f(x);
#else
  return exp2f(x);
#endif
}

// async global->LDS, 16B per lane. LDS dest is wave-uniform base + lane*16.
typedef const __attribute__((address_space(1))) void* gas1_t;
typedef __attribute__((address_space(3))) void* las3_t;
__device__ __forceinline__ void gload16(const void* g, void* l) {
  __builtin_amdgcn_global_load_lds((gas1_t)(unsigned long long)g,
                                   (las3_t)(unsigned int)(unsigned long long)l,
                                   16, 0, 0);
}

// ---------------------------------------------------------------------------
// Kernel 1 (fused): LayerNorm rows (blocks 0..4095) + weight bf16 cast
// (blocks 4096..8191).
// ---------------------------------------------------------------------------
__global__ __launch_bounds__(256) void ln_cast_kernel(const float* __restrict__ x,
                                                      const float* __restrict__ gamma,
                                                      const float* __restrict__ beta,
                                                      unsigned short* __restrict__ xn,
                                                      const float* __restrict__ w0,
                                                      const float* __restrict__ w1,
                                                      const float* __restrict__ w2,
                                                      const float* __restrict__ w3,
                                                      unsigned short* __restrict__ wdst) {
  const int t = threadIdx.x;
  if (blockIdx.x >= M_TOT) {
    const int cb = blockIdx.x - M_TOT;   // 0..4095
    const int y = cb >> 10;              // matrix index 0..3
    const float* s = (y == 0) ? w0 : (y == 1) ? w1 : (y == 2) ? w2 : w3;
    const int i = (cb & 1023) * 256 + t; // float4 index within matrix
    const float4 v = ((const float4*)s)[i];
    ushort4 o;
    o.x = f2bf(v.x);
    o.y = f2bf(v.y);
    o.z = f2bf(v.z);
    o.w = f2bf(v.w);
    ((ushort4*)(wdst + (size_t)y * H * H))[i] = o;
    return;
  }
  const int row = blockIdx.x;
  const float* xr = x + (size_t)row * H;
  float4 v = ((const float4*)xr)[t];
  float s = v.x + v.y + v.z + v.w;
  float s2 = v.x * v.x + v.y * v.y + v.z * v.z + v.w * v.w;
#pragma unroll
  for (int o = 32; o; o >>= 1) {
    s += __shfl_xor(s, o, 64);
    s2 += __shfl_xor(s2, o, 64);
  }
  __shared__ float red[8];
  const int wave = t >> 6;
  if ((t & 63) == 0) {
    red[wave] = s;
    red[wave + 4] = s2;
  }
  __syncthreads();
  const float ts = red[0] + red[1] + red[2] + red[3];
  const float ts2 = red[4] + red[5] + red[6] + red[7];
  const float mu = ts * (1.0f / (float)H);
  const float var = ts2 * (1.0f / (float)H) - mu * mu;
  const float rstd = rsqrtf(var + 1e-5f);
  const float4 g = ((const float4*)gamma)[t];
  const float4 b = ((const float4*)beta)[t];
  ushort4 o;
  o.x = f2bf((v.x - mu) * rstd * g.x + b.x);
  o.y = f2bf((v.y - mu) * rstd * g.y + b.y);
  o.z = f2bf((v.z - mu) * rstd * g.z + b.z);
  o.w = f2bf((v.w - mu) * rstd * g.w + b.w);
  ((ushort4*)(xn + (size_t)row * H))[t] = o;
}

// ---------------------------------------------------------------------------
// 128x128x(BK=32) bf16 MFMA GEMM (16x16x32, 32 KB LDS, double-buffered,
// one barrier per K-iter, 4 blocks/CU) with XCD-AWARE 1-D GRID. Used for the
// QKV GEMM (EPI=0, NPX=3): Q cols (<1024) scaled by C2_SCALE; cols<2048 ->
// qk natural; cols>=2048 -> V transposed vt[b][h*64+d][s].
// ---------------------------------------------------------------------------
template <int EPI, int NPX>
__global__ __launch_bounds__(256, 4) void gemm128(const unsigned short* __restrict__ A,
                                                  const unsigned short* __restrict__ W,
                                                  unsigned short* __restrict__ qk,
                                                  unsigned short* __restrict__ vt,
                                                  const float* __restrict__ bo,
                                                  const float* __restrict__ x,
                                                  float* __restrict__ out) {
  const int id = blockIdx.x;
  const int xcd = id & 7;
  const int r = id >> 3;
  const int nb = xcd * NPX + (r % NPX);
  const int mb = r / NPX;
  const int m0 = mb * 128;
  const int n0 = nb * 128;
  const int tid = threadIdx.x;
  const int wave = tid >> 6;
  const int lane = tid & 63;
  const int l16 = lane & 15;
  const int quad = lane >> 4;
  const int wx = wave & 1, wy = wave >> 1;

  __shared__ __align__(16) unsigned short As[2][128 * 32];
  __shared__ __align__(16) unsigned short Bs[2][128 * 32];

  // staging: wave stages 32 rows (2 gload16 instrs per matrix)
  const int sub = lane >> 2;       // row within 16-row group
  const int kcol = (lane & 3) * 8; // 4 lanes cover 32 cols
  const unsigned short* ag = A + (size_t)(m0 + wave * 32 + sub) * H + kcol;
  const unsigned short* bg = W + (size_t)(n0 + wave * 32 + sub) * H + kcol;
  const int lofs = wave * 32 * 32;

  f32x4 acc[4][4] = {};

  // prologue: stage k0=0 into buffer 0
  gload16(ag, &As[0][lofs]);
  gload16(ag + 16 * H, &As[0][lofs + 16 * 32]);
  gload16(bg, &Bs[0][lofs]);
  gload16(bg + 16 * H, &Bs[0][lofs + 16 * 32]);

  for (int it = 0; it < H / 32; it++) {
    const int bi = it & 1;
    __syncthreads(); // drains buf[bi] loads (issued a full iter ago)
    if (it + 1 < H / 32) {
      const int k1 = (it + 1) * 32;
      gload16(ag + k1, &As[bi ^ 1][lofs]);
      gload16(ag + k1 + 16 * H, &As[bi ^ 1][lofs + 16 * 32]);
      gload16(bg + k1, &Bs[bi ^ 1][lofs]);
      gload16(bg + k1 + 16 * H, &Bs[bi ^ 1][lofs + 16 * 32]);
    }
    bf16x8 af[4], bf[4];
#pragma unroll
    for (int t = 0; t < 4; t++) {
      af[t] = *(const bf16x8*)&As[bi][(wy * 64 + t * 16 + l16) * 32 + quad * 8];
      bf[t] = *(const bf16x8*)&Bs[bi][(wx * 64 + t * 16 + l16) * 32 + quad * 8];
    }
#pragma unroll
    for (int i = 0; i < 4; i++)
#pragma unroll
      for (int j = 0; j < 4; j++)
        acc[i][j] = __builtin_amdgcn_mfma_f32_16x16x32_bf16(af[i], bf[j], acc[i][j], 0, 0, 0);
  }

  if (EPI == 0) {
#pragma unroll
    for (int j = 0; j < 4; j++) {
      const int cb = n0 + wx * 64 + j * 16; // wave-uniform tile col base
      if (cb < 2048) {
        const float qs = (cb < 1024) ? C2_SCALE : 1.0f;
#pragma unroll
        for (int i = 0; i < 4; i++) {
          const int row = m0 + wy * 64 + i * 16 + quad * 4;
#pragma unroll
          for (int r2 = 0; r2 < 4; r2++)
            qk[(size_t)(row + r2) * 2048 + cb + l16] = f2bf(acc[i][j][r2] * qs);
        }
      } else {
        const int n = cb + l16 - 2048; // h*64+d
#pragma unroll
        for (int i = 0; i < 4; i++) {
          const int row0 = m0 + wy * 64 + i * 16 + quad * 4;
          const int b = row0 >> 11;
          const int s = row0 & 2047;
          ushort4 p;
          p.x = f2bf(acc[i][j][0]);
          p.y = f2bf(acc[i][j][1]);
          p.z = f2bf(acc[i][j][2]);
          p.w = f2bf(acc[i][j][3]);
          *(ushort4*)&vt[((size_t)b * 1024 + n) * SEQ + s] = p;
        }
      }
    }
  } else {
#pragma unroll
    for (int j = 0; j < 4; j++) {
      const int col = n0 + wx * 64 + j * 16 + l16;
      const float bv = bo[col];
#pragma unroll
      for (int i = 0; i < 4; i++) {
        const int row = m0 + wy * 64 + i * 16 + quad * 4;
#pragma unroll
        for (int r2 = 0; r2 < 4; r2++) {
          const size_t idx = (size_t)(row + r2) * H + col;
          out[idx] = acc[i][j][r2] + bv + x[idx];
        }
      }
    }
  }
}

// ---------------------------------------------------------------------------
// Proj GEMM: 64x128x(BK=32) tiles -> grid 512 blocks = 2 blocks/CU.
// LDS 24 KB. Epilogue: out = acc + bo[col] + x.
// Grid: id&7 = N-block (== XCD, Wo 128-col slice L2-resident), id>>3 = M-block.
// ---------------------------------------------------------------------------
__global__ __launch_bounds__(256, 4) void proj64(const unsigned short* __restrict__ A,
                                                 const unsigned short* __restrict__ W,
                                                 const float* __restrict__ bo,
                                                 const float* __restrict__ x,
                                                 float* __restrict__ out) {
  const int id = blockIdx.x; // 512 blocks
  const int nb = id & 7;     // N-block = XCD
  const int mb = id >> 3;    // 0..63
  const int m0 = mb * 64;
  const int n0 = nb * 128;
  const int tid = threadIdx.x;
  const int wave = tid >> 6;
  const int lane = tid & 63;
  const int l16 = lane & 15;
  const int quad = lane >> 4;
  const int wx = wave & 1, wy = wave >> 1;

  __shared__ __align__(16) unsigned short As[2][64 * 32];
  __shared__ __align__(16) unsigned short Bs[2][128 * 32];

  // staging: wave stages 16 A-rows (1 gload16) + 32 B-rows (2 gload16)
  const int sub = lane >> 2;       // row within 16-row group
  const int kcol = (lane & 3) * 8; // 4 lanes cover 32 cols
  const unsigned short* ag = A + (size_t)(m0 + wave * 16 + sub) * H + kcol;
  const unsigned short* bg = W + (size_t)(n0 + wave * 32 + sub) * H + kcol;
  const int lofsA = wave * 16 * 32;
  const int lofsB = wave * 32 * 32;

  f32x4 acc[2][4] = {};

  // prologue: stage k0=0 into buffer 0
  gload16(ag, &As[0][lofsA]);
  gload16(bg, &Bs[0][lofsB]);
  gload16(bg + 16 * H, &Bs[0][lofsB + 16 * 32]);

  for (int it = 0; it < H / 32; it++) {
    const int bi = it & 1;
    __syncthreads(); // drains buf[bi] loads (issued a full iter ago)
    if (it + 1 < H / 32) {
      const int k1 = (it + 1) * 32;
      gload16(ag + k1, &As[bi ^ 1][lofsA]);
      gload16(bg + k1, &Bs[bi ^ 1][lofsB]);
      gload16(bg + k1 + 16 * H, &Bs[bi ^ 1][lofsB + 16 * 32]);
    }
    bf16x8 af[2], bf[4];
#pragma unroll
    for (int t = 0; t < 2; t++)
      af[t] = *(const bf16x8*)&As[bi][(wy * 32 + t * 16 + l16) * 32 + quad * 8];
#pragma unroll
    for (int t = 0; t < 4; t++)
      bf[t] = *(const bf16x8*)&Bs[bi][(wx * 64 + t * 16 + l16) * 32 + quad * 8];
#pragma unroll
    for (int i = 0; i < 2; i++)
#pragma unroll
      for (int j = 0; j < 4; j++)
        acc[i][j] = __builtin_amdgcn_mfma_f32_16x16x32_bf16(af[i], bf[j], acc[i][j], 0, 0, 0);
  }

#pragma unroll
  for (int j = 0; j < 4; j++) {
    const int col = n0 + wx * 64 + j * 16 + l16;
    const float bv = bo[col];
#pragma unroll
    for (int i = 0; i < 2; i++) {
      const int row = m0 + wy * 32 + i * 16 + quad * 4;
#pragma unroll
      for (int r2 = 0; r2 < 4; r2++) {
        const size_t idx = (size_t)(row + r2) * H + col;
        out[idx] = acc[i][j][r2] + bv + x[idx];
      }
    }
  }
}

// ---------------------------------------------------------------------------
// Flash attention v10: v5 compute (32x32x16, in-register P via cvt_pk +
// permlane32_swap) with KVBLK=128: 16 iters (half the barriers), 4 QK m-tiles
// + 8 PV s-chunks per iter (2x independent work per phase for intra-iter
// overlap: QK(mt2,3) MFMAs issue under exp2(mt0,1)).
//   - K LDS: [s=0..127][64 d-shorts], 16x 1KB chunks, 8-row XOR swizzle (as v5).
//   - V LDS: TWO 64-s half-tiles of [d=0..63][64 s-shorts] each (preserves the
//     3-bit swizzle depth; a single 128-short row would be a 16-way conflict).
//   - P->B-frag permlane formula extends linearly: n=2sc(+1), mt=n>>2, b=n&3.
// LDS 64 KB, 2 blocks/CU. Grid 512 blocks, XCD-supertiled (unchanged).
// ---------------------------------------------------------------------------
__global__ __launch_bounds__(256, 2) void attn_kernel(const unsigned short* __restrict__ qk,
                                                      const unsigned short* __restrict__ vt,
                                                      unsigned short* __restrict__ O) {
  const int id = blockIdx.x; // 512 blocks
  const int xcd = id & 7;
  const int slot = id >> 3;       // 0..63
  const int qt = slot & 15;       // q-tile within (b,h)
  const int g = slot >> 4;        // 0..3
  const int combo = xcd * 4 + g;  // 0..31
  const int h = combo & 15;
  const int b = combo >> 4;
  const int tid = threadIdx.x;
  const int wave = tid >> 6;
  const int lane = tid & 63;
  const int l31 = lane & 31;
  const int l7 = lane & 7;
  const int hi = lane >> 5;

  __shared__ __align__(16) unsigned short Kt[2][128 * 64];   // [s][d] 32 KB
  __shared__ __align__(16) unsigned short Vt[2][2][64 * 64]; // [half][d][s] 32 KB

  const unsigned short* Qbase = qk + (size_t)b * SEQ * 2048 + h * 64;
  const unsigned short* Kbase = qk + (size_t)b * SEQ * 2048 + 1024 + h * 64;
  const unsigned short* Vbase = vt + ((size_t)b * 1024 + h * 64) * SEQ;

  // staging geometry: one gload16 covers 8 rows x 64 shorts (1 KB), XOR swizzle
  const int rIn = lane >> 3;
  const int gsw = (lane & 7) ^ rIn;

  // Q fragments (B-operand, hoisted): B[n=l31 -> qrow][k=hi*8+e -> d in chunk kc]
  const int qrow = qt * 128 + wave * 32 + l31;
  bf16x8 aq[4];
#pragma unroll
  for (int kc = 0; kc < 4; kc++)
    aq[kc] = *(const bf16x8*)(Qbase + (size_t)qrow * 2048 + kc * 16 + hi * 8);

  f32x16 o_acc[2] = {}; // [dt] O^T: col=l31=qrow, row=(reg&3)+8*(reg>>2)+4*hi -> d
  float lc[4] = {};     // partial denominators (4 chains)

  // prologue: stage tile 0 into buffer 0 (4 K-chunks + 4 V-chunks per wave)
#pragma unroll
  for (int c = 0; c < 4; c++) {
    const int ch = wave * 4 + c; // 0..15
    const int krow = ch * 8 + rIn;
    gload16(Kbase + (size_t)krow * 2048 + gsw * 8, &Kt[0][ch * 512]);
    const int half = ch >> 3, sub = ch & 7;
    const int vrow = sub * 8 + rIn;
    gload16(Vbase + (size_t)vrow * SEQ + half * 64 + gsw * 8, &Vt[0][half][sub * 512]);
  }

#pragma unroll 2
  for (int it = 0; it < SEQ / 128; it++) {
    const int bi = it & 1;
    __syncthreads(); // waits cur-buffer loads (vmcnt) + prev iter readers done
    if (it + 1 < SEQ / 128) {
#pragma unroll
      for (int c = 0; c < 4; c++) {
        const int ch = wave * 4 + c;
        const int krow = ch * 8 + rIn;
        gload16(Kbase + (size_t)((it + 1) * 128 + krow) * 2048 + gsw * 8,
                &Kt[bi ^ 1][ch * 512]);
        const int half = ch >> 3, sub = ch & 7;
        const int vrow = sub * 8 + rIn;
        gload16(Vbase + (size_t)vrow * SEQ + (it + 1) * 128 + half * 64 + gsw * 8,
                &Vt[bi ^ 1][half][sub * 512]);
      }
    }

    unsigned int w[4][8]; // [mt][gi]: P words for s = 32*mt + pattern

    // ---- pass A: mt 0,1 -> QK, softmax ----
    {
      f32x16 sa = {}, sb = {};
#pragma unroll
      for (int kc = 0; kc < 4; kc++) {
        const bf16x8 kf0 = *(const bf16x8*)&Kt[bi][(l31)*64 + ((kc * 16 + hi * 8) ^ (l7 * 8))];
        const bf16x8 kf1 =
            *(const bf16x8*)&Kt[bi][(32 + l31) * 64 + ((kc * 16 + hi * 8) ^ (l7 * 8))];
        sa = __builtin_amdgcn_mfma_f32_32x32x16_bf16(kf0, aq[kc], sa, 0, 0, 0);
        sb = __builtin_amdgcn_mfma_f32_32x32x16_bf16(kf1, aq[kc], sb, 0, 0, 0);
      }
      {
        float p[16];
#pragma unroll
        for (int r2 = 0; r2 < 16; r2++) p[r2] = fast_exp2(sa[r2]);
        lc[0] += ((p[0] + p[1]) + (p[2] + p[3])) + ((p[8] + p[9]) + (p[10] + p[11]));
        lc[1] += ((p[4] + p[5]) + (p[6] + p[7])) + ((p[12] + p[13]) + (p[14] + p[15]));
#pragma unroll
        for (int gi = 0; gi < 8; gi++) w[0][gi] = pkbf(p[2 * gi], p[2 * gi + 1]);
      }
      {
        float p[16];
#pragma unroll
        for (int r2 = 0; r2 < 16; r2++) p[r2] = fast_exp2(sb[r2]);
        lc[2] += ((p[0] + p[1]) + (p[2] + p[3])) + ((p[8] + p[9]) + (p[10] + p[11]));
        lc[3] += ((p[4] + p[5]) + (p[6] + p[7])) + ((p[12] + p[13]) + (p[14] + p[15]));
#pragma unroll
        for (int gi = 0; gi < 8; gi++) w[1][gi] = pkbf(p[2 * gi], p[2 * gi + 1]);
      }
    }

    // ---- pass B: mt 2,3 -> QK, softmax ----
    {
      f32x16 sa = {}, sb = {};
#pragma unroll
      for (int kc = 0; kc < 4; kc++) {
        const bf16x8 kf0 =
            *(const bf16x8*)&Kt[bi][(64 + l31) * 64 + ((kc * 16 + hi * 8) ^ (l7 * 8))];
        const bf16x8 kf1 =
            *(const bf16x8*)&Kt[bi][(96 + l31) * 64 + ((kc * 16 + hi * 8) ^ (l7 * 8))];
        sa = __builtin_amdgcn_mfma_f32_32x32x16_bf16(kf0, aq[kc], sa, 0, 0, 0);
        sb = __builtin_amdgcn_mfma_f32_32x32x16_bf16(kf1, aq[kc], sb, 0, 0, 0);
      }
      {
        float p[16];
#pragma unroll
        for (int r2 = 0; r2 < 16; r2++) p[r2] = fast_exp2(sa[r2]);
        lc[0] += ((p[0] + p[1]) + (p[2] + p[3])) + ((p[8] + p[9]) + (p[10] + p[11]));
        lc[1] += ((p[4] + p[5]) + (p[6] + p[7])) + ((p[12] + p[13]) + (p[14] + p[15]));
#pragma unroll
        for (int gi = 0; gi < 8; gi++) w[2][gi] = pkbf(p[2 * gi], p[2 * gi + 1]);
      }
      {
        float p[16];
#pragma unroll
        for (int r2 = 0; r2 < 16; r2++) p[r2] = fast_exp2(sb[r2]);
        lc[2] += ((p[0] + p[1]) + (p[2] + p[3])) + ((p[8] + p[9]) + (p[10] + p[11]));
        lc[3] += ((p[4] + p[5]) + (p[6] + p[7])) + ((p[12] + p[13]) + (p[14] + p[15]));
#pragma unroll
        for (int gi = 0; gi < 8; gi++) w[3][gi] = pkbf(p[2 * gi], p[2 * gi + 1]);
      }
    }

    // ---- PV: O^T += V^T (A) @ P^T (B), 8 s-chunks ----
#pragma unroll
    for (int sc = 0; sc < 8; sc++) {
      const int n0i = 2 * sc, n1i = 2 * sc + 1;
      const int mt0 = n0i >> 2, b0 = n0i & 3;
      const int mt1 = n1i >> 2, b1 = n1i & 3;
      const auto rA = __builtin_amdgcn_permlane32_swap(w[mt0][2 * b0], w[mt1][2 * b1],
                                                       false, false);
      const auto rB = __builtin_amdgcn_permlane32_swap(w[mt0][2 * b0 + 1], w[mt1][2 * b1 + 1],
                                                       false, false);
      union { unsigned int u[4]; bf16x8 v; } pb;
      pb.u[0] = rA[0]; // k = sc*16+hi*8 + {0,1}
      pb.u[1] = rB[0]; // + {2,3}
      pb.u[2] = rA[1]; // + {4,5}
      pb.u[3] = rB[1]; // + {6,7}
      const int half = sc >> 2, sch = sc & 3;
#pragma unroll
      for (int dt = 0; dt < 2; dt++) {
        const bf16x8 vf = *(const bf16x8*)&Vt[bi][half][(dt * 32 + l31) * 64 +
                                                       ((sch * 16 + hi * 8) ^ (l7 * 8))];
        o_acc[dt] = __builtin_amdgcn_mfma_f32_32x32x16_bf16(vf, pb.v, o_acc[dt], 0, 0, 0);
      }
    }
  }

  // epilogue: lanes l and l|32 hold complementary s-subsets of the same qrow
  float lsum = (lc[0] + lc[1]) + (lc[2] + lc[3]);
  const float l_i = lsum + __shfl_xor(lsum, 32, 64);
  const float inv = 1.0f / l_i;
  unsigned short* orow = O + ((size_t)(b * SEQ + qrow)) * H + h * 64;
#pragma unroll
  for (int dt = 0; dt < 2; dt++)
#pragma unroll
    for (int rg = 0; rg < 4; rg++) {
      uint2 d;
      d.x = pkbf(o_acc[dt][4 * rg + 0] * inv, o_acc[dt][4 * rg + 1] * inv);
      d.y = pkbf(o_acc[dt][4 * rg + 2] * inv, o_acc[dt][4 * rg + 3] * inv);
      *(uint2*)&orow[dt * 32 + 8 * rg + 4 * hi] = d;
    }
}

// ---------------------------------------------------------------------------
extern "C" void kernel_launch(void* const* d_in, const int* in_sizes, int n_in,
                              void* d_out, int out_size, void* d_ws, size_t ws_size,
                              hipStream_t stream) {
  const float* x = (const float*)d_in[0];
  const float* Wq = (const float*)d_in[1];
  const float* Wk = (const float*)d_in[2];
  const float* Wv = (const float*)d_in[3];
  const float* Wo = (const float*)d_in[4];
  const float* bo = (const float*)d_in[5];
  const float* gamma = (const float*)d_in[6];
  const float* beta = (const float*)d_in[7];
  float* out = (float*)d_out;

  unsigned short* ws = (unsigned short*)d_ws;
  unsigned short* xn = ws;                              // 4096*1024
  unsigned short* wcat = xn + (size_t)M_TOT * H;        // 4*1024*1024 (Wq,Wk,Wv,Wo)
  unsigned short* wob = wcat + (size_t)3 * H * H;
  unsigned short* qkb = wcat + (size_t)4 * H * H;       // 4096*2048 (Q | K)
  unsigned short* vtb = qkb + (size_t)M_TOT * 2048;     // 2*1024*2048 (V^T)
  unsigned short* atb = vtb + (size_t)BATCH * H * SEQ;  // 4096*1024

  ln_cast_kernel<<<M_TOT + 4096, 256, 0, stream>>>(x, gamma, beta, xn, Wq, Wk, Wv, Wo,
                                                   wcat);
  // QKV: 32 M-blocks x 24 N-blocks, XCD-supertiled (3 N-blocks per XCD)
  gemm128<0, 3><<<(M_TOT / 128) * (NQKV / 128), 256, 0, stream>>>(
      xn, wcat, qkb, vtb, nullptr, nullptr, nullptr);
  // attn: 512 blocks (128-row q-tiles), XCD-supertiled (4 (b,h) combos per XCD)
  attn_kernel<<<(SEQ / 128) * NHEAD * BATCH, 256, 0, stream>>>(qkb, vtb, atb);
  // proj: 64 M-blocks x 8 N-blocks = 512 blocks (2 blocks/CU)
  proj64<<<(M_TOT / 64) * (H / 128), 256, 0, stream>>>(atb, wob, bo, x, out);
}

// Round 7
// 185.865 us; speedup vs baseline: 1.4314x; 1.0044x over previous
//
#include <hip/hip_runtime.h>
#include <hip/hip_bf16.h>

// Problem constants
#define H 1024
#define NHEAD 16
#define HDIM 64
#define SEQ 2048
#define BATCH 2
#define M_TOT (BATCH * SEQ) // 4096 tokens
#define NQKV 3072           // fused QKV output cols

typedef __attribute__((ext_vector_type(8))) short bf16x8;  // 8 bf16 = 4 VGPRs (MFMA A/B frag)
typedef __attribute__((ext_vector_type(4))) float f32x4;   // 16x16 MFMA C/D frag
typedef __attribute__((ext_vector_type(16))) float f32x16; // 32x32 MFMA C/D frag

// (1/sqrt(HDIM)) * log2(e), folded into Q at the QKV-GEMM epilogue
#define C2_SCALE 0.18033688f

__device__ __forceinline__ unsigned short f2bf(float f) {
  union { float f; unsigned int u; } a;
  a.f = f;
  unsigned int u = a.u;
  return (unsigned short)((u + 0x7fffu + ((u >> 16) & 1u)) >> 16); // RNE
}

// packed f32x2 -> bf16x2 (v_cvt_pk_bf16_f32), low short = first arg
__device__ __forceinline__ unsigned int pkbf(float a, float b) {
  union { __hip_bfloat162 h; unsigned int u; } cv;
  cv.h = __float22bfloat162_rn(float2{a, b});
  return cv.u;
}

__device__ __forceinline__ float fast_exp2(float x) {
#if defined(__has_builtin) && __has_builtin(__builtin_amdgcn_exp2f)
  return __builtin_amdgcn_exp2f(x);
#else
  return exp2f(x);
#endif
}

// async global->LDS, 16B per lane. LDS dest is wave-uniform base + lane*16.
typedef const __attribute__((address_space(1))) void* gas1_t;
typedef __attribute__((address_space(3))) void* las3_t;
__device__ __forceinline__ void gload16(const void* g, void* l) {
  __builtin_amdgcn_global_load_lds((gas1_t)(unsigned long long)g,
                                   (las3_t)(unsigned int)(unsigned long long)l,
                                   16, 0, 0);
}

// ---------------------------------------------------------------------------
// Kernel 1 (fused): LayerNorm rows (blocks 0..4095) + weight bf16 cast
// (blocks 4096..8191).
// ---------------------------------------------------------------------------
__global__ __launch_bounds__(256) void ln_cast_kernel(const float* __restrict__ x,
                                                      const float* __restrict__ gamma,
                                                      const float* __restrict__ beta,
                                                      unsigned short* __restrict__ xn,
                                                      const float* __restrict__ w0,
                                                      const float* __restrict__ w1,
                                                      const float* __restrict__ w2,
                                                      const float* __restrict__ w3,
                                                      unsigned short* __restrict__ wdst) {
  const int t = threadIdx.x;
  if (blockIdx.x >= M_TOT) {
    const int cb = blockIdx.x - M_TOT;   // 0..4095
    const int y = cb >> 10;              // matrix index 0..3
    const float* s = (y == 0) ? w0 : (y == 1) ? w1 : (y == 2) ? w2 : w3;
    const int i = (cb & 1023) * 256 + t; // float4 index within matrix
    const float4 v = ((const float4*)s)[i];
    ushort4 o;
    o.x = f2bf(v.x);
    o.y = f2bf(v.y);
    o.z = f2bf(v.z);
    o.w = f2bf(v.w);
    ((ushort4*)(wdst + (size_t)y * H * H))[i] = o;
    return;
  }
  const int row = blockIdx.x;
  const float* xr = x + (size_t)row * H;
  float4 v = ((const float4*)xr)[t];
  float s = v.x + v.y + v.z + v.w;
  float s2 = v.x * v.x + v.y * v.y + v.z * v.z + v.w * v.w;
#pragma unroll
  for (int o = 32; o; o >>= 1) {
    s += __shfl_xor(s, o, 64);
    s2 += __shfl_xor(s2, o, 64);
  }
  __shared__ float red[8];
  const int wave = t >> 6;
  if ((t & 63) == 0) {
    red[wave] = s;
    red[wave + 4] = s2;
  }
  __syncthreads();
  const float ts = red[0] + red[1] + red[2] + red[3];
  const float ts2 = red[4] + red[5] + red[6] + red[7];
  const float mu = ts * (1.0f / (float)H);
  const float var = ts2 * (1.0f / (float)H) - mu * mu;
  const float rstd = rsqrtf(var + 1e-5f);
  const float4 g = ((const float4*)gamma)[t];
  const float4 b = ((const float4*)beta)[t];
  ushort4 o;
  o.x = f2bf((v.x - mu) * rstd * g.x + b.x);
  o.y = f2bf((v.y - mu) * rstd * g.y + b.y);
  o.z = f2bf((v.z - mu) * rstd * g.z + b.z);
  o.w = f2bf((v.w - mu) * rstd * g.w + b.w);
  ((ushort4*)(xn + (size_t)row * H))[t] = o;
}

// ---------------------------------------------------------------------------
// QKV GEMM v11: 128x128x(BK=32), 16x16x32 MFMA, THREE LDS buffers with a
// 2-tiles-ahead counted-vmcnt pipeline (T4):
//   per iter: s_waitcnt vmcnt(4)  (own tile-it loads retired; tile-(it+1)'s
//   4 stay in flight) -> raw s_barrier (no vmcnt(0) drain!) -> stage tile
//   it+2 -> ds_read + MFMA. Each staged tile gets ~2 iterations (>=400 cyc)
//   to land. Last iteration peeled with vmcnt(0).
// Safety: a wave's MFMAs (lgkmcnt-gated on its ds_reads) precede its barrier
// arrival, so when any wave stages buf[(it+2)%3] after barrier(it), all
// readers of that buffer (iter it-1) are done. Single barrier per iter.
// LDS 48 KB -> 3 blocks/CU (grid 768 = 3/CU). XCD-supertiled grid (NPX=3).
// Epilogue: Q cols scaled by C2_SCALE; V cols stored transposed.
// ---------------------------------------------------------------------------
template <int EPI, int NPX>
__global__ __launch_bounds__(256, 3) void gemm128p(const unsigned short* __restrict__ A,
                                                   const unsigned short* __restrict__ W,
                                                   unsigned short* __restrict__ qk,
                                                   unsigned short* __restrict__ vt,
                                                   const float* __restrict__ bo,
                                                   const float* __restrict__ x,
                                                   float* __restrict__ out) {
  const int id = blockIdx.x;
  const int xcd = id & 7;
  const int r = id >> 3;
  const int nb = xcd * NPX + (r % NPX);
  const int mb = r / NPX;
  const int m0 = mb * 128;
  const int n0 = nb * 128;
  const int tid = threadIdx.x;
  const int wave = tid >> 6;
  const int lane = tid & 63;
  const int l16 = lane & 15;
  const int quad = lane >> 4;
  const int wx = wave & 1, wy = wave >> 1;

  __shared__ __align__(16) unsigned short As[3][128 * 32];
  __shared__ __align__(16) unsigned short Bs[3][128 * 32];

  // staging: wave stages 32 rows (2 gload16 instrs per matrix) = 4 instrs
  const int sub = lane >> 2;       // row within 16-row group
  const int kcol = (lane & 3) * 8; // 4 lanes cover 32 cols
  const unsigned short* ag = A + (size_t)(m0 + wave * 32 + sub) * H + kcol;
  const unsigned short* bg = W + (size_t)(n0 + wave * 32 + sub) * H + kcol;
  const int lofs = wave * 32 * 32;

  f32x4 acc[4][4] = {};

  auto stage = [&](int t, int B) {
    const int k1 = t * 32;
    gload16(ag + k1, &As[B][lofs]);
    gload16(ag + k1 + 16 * H, &As[B][lofs + 16 * 32]);
    gload16(bg + k1, &Bs[B][lofs]);
    gload16(bg + k1 + 16 * H, &Bs[B][lofs + 16 * 32]);
  };
  auto compute = [&](int bi) {
    bf16x8 af[4], bf[4];
#pragma unroll
    for (int t = 0; t < 4; t++) {
      af[t] = *(const bf16x8*)&As[bi][(wy * 64 + t * 16 + l16) * 32 + quad * 8];
      bf[t] = *(const bf16x8*)&Bs[bi][(wx * 64 + t * 16 + l16) * 32 + quad * 8];
    }
#pragma unroll
    for (int i = 0; i < 4; i++)
#pragma unroll
      for (int j = 0; j < 4; j++)
        acc[i][j] = __builtin_amdgcn_mfma_f32_16x16x32_bf16(af[i], bf[j], acc[i][j], 0, 0, 0);
  };

  // prologue: stage tiles 0,1 (8 loads/wave outstanding)
  stage(0, 0);
  stage(1, 1);

  for (int it = 0; it < H / 32 - 1; it++) {
    asm volatile("s_waitcnt vmcnt(4)" ::: "memory"); // tile it landed (own)
    __builtin_amdgcn_s_barrier();                    // all waves' tile it landed
    if (it + 2 < H / 32) stage(it + 2, (it + 2) % 3);
    compute(it % 3);
  }
  // peeled last iteration: drain everything
  asm volatile("s_waitcnt vmcnt(0)" ::: "memory");
  __builtin_amdgcn_s_barrier();
  compute((H / 32 - 1) % 3);

  if (EPI == 0) {
#pragma unroll
    for (int j = 0; j < 4; j++) {
      const int cb = n0 + wx * 64 + j * 16; // wave-uniform tile col base
      if (cb < 2048) {
        const float qs = (cb < 1024) ? C2_SCALE : 1.0f;
#pragma unroll
        for (int i = 0; i < 4; i++) {
          const int row = m0 + wy * 64 + i * 16 + quad * 4;
#pragma unroll
          for (int r2 = 0; r2 < 4; r2++)
            qk[(size_t)(row + r2) * 2048 + cb + l16] = f2bf(acc[i][j][r2] * qs);
        }
      } else {
        const int n = cb + l16 - 2048; // h*64+d
#pragma unroll
        for (int i = 0; i < 4; i++) {
          const int row0 = m0 + wy * 64 + i * 16 + quad * 4;
          const int b = row0 >> 11;
          const int s = row0 & 2047;
          ushort4 p;
          p.x = f2bf(acc[i][j][0]);
          p.y = f2bf(acc[i][j][1]);
          p.z = f2bf(acc[i][j][2]);
          p.w = f2bf(acc[i][j][3]);
          *(ushort4*)&vt[((size_t)b * 1024 + n) * SEQ + s] = p;
        }
      }
    }
  } else {
#pragma unroll
    for (int j = 0; j < 4; j++) {
      const int col = n0 + wx * 64 + j * 16 + l16;
      const float bv = bo[col];
#pragma unroll
      for (int i = 0; i < 4; i++) {
        const int row = m0 + wy * 64 + i * 16 + quad * 4;
#pragma unroll
        for (int r2 = 0; r2 < 4; r2++) {
          const size_t idx = (size_t)(row + r2) * H + col;
          out[idx] = acc[i][j][r2] + bv + x[idx];
        }
      }
    }
  }
}

// ---------------------------------------------------------------------------
// Proj GEMM v11: 64x128x(BK=32) tiles, same 3-buffer counted-vmcnt pipeline
// (3 loads/stage -> vmcnt(3)). LDS 36 KB. Grid 512 = 2 blocks/CU.
// Epilogue: out = acc + bo[col] + x. id&7 = N-block (== XCD).
// ---------------------------------------------------------------------------
__global__ __launch_bounds__(256, 4) void proj64p(const unsigned short* __restrict__ A,
                                                  const unsigned short* __restrict__ W,
                                                  const float* __restrict__ bo,
                                                  const float* __restrict__ x,
                                                  float* __restrict__ out) {
  const int id = blockIdx.x; // 512 blocks
  const int nb = id & 7;     // N-block = XCD
  const int mb = id >> 3;    // 0..63
  const int m0 = mb * 64;
  const int n0 = nb * 128;
  const int tid = threadIdx.x;
  const int wave = tid >> 6;
  const int lane = tid & 63;
  const int l16 = lane & 15;
  const int quad = lane >> 4;
  const int wx = wave & 1, wy = wave >> 1;

  __shared__ __align__(16) unsigned short As[3][64 * 32];
  __shared__ __align__(16) unsigned short Bs[3][128 * 32];

  // staging: wave stages 16 A-rows (1 gload16) + 32 B-rows (2 gload16)
  const int sub = lane >> 2;       // row within 16-row group
  const int kcol = (lane & 3) * 8; // 4 lanes cover 32 cols
  const unsigned short* ag = A + (size_t)(m0 + wave * 16 + sub) * H + kcol;
  const unsigned short* bg = W + (size_t)(n0 + wave * 32 + sub) * H + kcol;
  const int lofsA = wave * 16 * 32;
  const int lofsB = wave * 32 * 32;

  f32x4 acc[2][4] = {};

  auto stage = [&](int t, int B) {
    const int k1 = t * 32;
    gload16(ag + k1, &As[B][lofsA]);
    gload16(bg + k1, &Bs[B][lofsB]);
    gload16(bg + k1 + 16 * H, &Bs[B][lofsB + 16 * 32]);
  };
  auto compute = [&](int bi) {
    bf16x8 af[2], bf[4];
#pragma unroll
    for (int t = 0; t < 2; t++)
      af[t] = *(const bf16x8*)&As[bi][(wy * 32 + t * 16 + l16) * 32 + quad * 8];
#pragma unroll
    for (int t = 0; t < 4; t++)
      bf[t] = *(const bf16x8*)&Bs[bi][(wx * 64 + t * 16 + l16) * 32 + quad * 8];
#pragma unroll
    for (int i = 0; i < 2; i++)
#pragma unroll
      for (int j = 0; j < 4; j++)
        acc[i][j] = __builtin_amdgcn_mfma_f32_16x16x32_bf16(af[i], bf[j], acc[i][j], 0, 0, 0);
  };

  stage(0, 0);
  stage(1, 1); // 6 loads/wave outstanding

  for (int it = 0; it < H / 32 - 1; it++) {
    asm volatile("s_waitcnt vmcnt(3)" ::: "memory"); // tile it landed (own)
    __builtin_amdgcn_s_barrier();
    if (it + 2 < H / 32) stage(it + 2, (it + 2) % 3);
    compute(it % 3);
  }
  asm volatile("s_waitcnt vmcnt(0)" ::: "memory");
  __builtin_amdgcn_s_barrier();
  compute((H / 32 - 1) % 3);

#pragma unroll
  for (int j = 0; j < 4; j++) {
    const int col = n0 + wx * 64 + j * 16 + l16;
    const float bv = bo[col];
#pragma unroll
    for (int i = 0; i < 2; i++) {
      const int row = m0 + wy * 32 + i * 16 + quad * 4;
#pragma unroll
      for (int r2 = 0; r2 < 4; r2++) {
        const size_t idx = (size_t)(row + r2) * H + col;
        out[idx] = acc[i][j][r2] + bv + x[idx];
      }
    }
  }
}

// ---------------------------------------------------------------------------
// Flash attention v10 (best: 46.9 us — UNCHANGED this round, control):
// 32x32x16 in-register-P, KVBLK=128, 16 iters, LDS 64 KB, 512 blocks.
// ---------------------------------------------------------------------------
__global__ __launch_bounds__(256, 2) void attn_kernel(const unsigned short* __restrict__ qk,
                                                      const unsigned short* __restrict__ vt,
                                                      unsigned short* __restrict__ O) {
  const int id = blockIdx.x; // 512 blocks
  const int xcd = id & 7;
  const int slot = id >> 3;       // 0..63
  const int qt = slot & 15;       // q-tile within (b,h)
  const int g = slot >> 4;        // 0..3
  const int combo = xcd * 4 + g;  // 0..31
  const int h = combo & 15;
  const int b = combo >> 4;
  const int tid = threadIdx.x;
  const int wave = tid >> 6;
  const int lane = tid & 63;
  const int l31 = lane & 31;
  const int l7 = lane & 7;
  const int hi = lane >> 5;

  __shared__ __align__(16) unsigned short Kt[2][128 * 64];   // [s][d] 32 KB
  __shared__ __align__(16) unsigned short Vt[2][2][64 * 64]; // [half][d][s] 32 KB

  const unsigned short* Qbase = qk + (size_t)b * SEQ * 2048 + h * 64;
  const unsigned short* Kbase = qk + (size_t)b * SEQ * 2048 + 1024 + h * 64;
  const unsigned short* Vbase = vt + ((size_t)b * 1024 + h * 64) * SEQ;

  // staging geometry: one gload16 covers 8 rows x 64 shorts (1 KB), XOR swizzle
  const int rIn = lane >> 3;
  const int gsw = (lane & 7) ^ rIn;

  // Q fragments (B-operand, hoisted): B[n=l31 -> qrow][k=hi*8+e -> d in chunk kc]
  const int qrow = qt * 128 + wave * 32 + l31;
  bf16x8 aq[4];
#pragma unroll
  for (int kc = 0; kc < 4; kc++)
    aq[kc] = *(const bf16x8*)(Qbase + (size_t)qrow * 2048 + kc * 16 + hi * 8);

  f32x16 o_acc[2] = {}; // [dt] O^T: col=l31=qrow, row=(reg&3)+8*(reg>>2)+4*hi -> d
  float lc[4] = {};     // partial denominators (4 chains)

  // prologue: stage tile 0 into buffer 0 (4 K-chunks + 4 V-chunks per wave)
#pragma unroll
  for (int c = 0; c < 4; c++) {
    const int ch = wave * 4 + c; // 0..15
    const int krow = ch * 8 + rIn;
    gload16(Kbase + (size_t)krow * 2048 + gsw * 8, &Kt[0][ch * 512]);
    const int half = ch >> 3, sub = ch & 7;
    const int vrow = sub * 8 + rIn;
    gload16(Vbase + (size_t)vrow * SEQ + half * 64 + gsw * 8, &Vt[0][half][sub * 512]);
  }

#pragma unroll 2
  for (int it = 0; it < SEQ / 128; it++) {
    const int bi = it & 1;
    __syncthreads(); // waits cur-buffer loads (vmcnt) + prev iter readers done
    if (it + 1 < SEQ / 128) {
#pragma unroll
      for (int c = 0; c < 4; c++) {
        const int ch = wave * 4 + c;
        const int krow = ch * 8 + rIn;
        gload16(Kbase + (size_t)((it + 1) * 128 + krow) * 2048 + gsw * 8,
                &Kt[bi ^ 1][ch * 512]);
        const int half = ch >> 3, sub = ch & 7;
        const int vrow = sub * 8 + rIn;
        gload16(Vbase + (size_t)vrow * SEQ + (it + 1) * 128 + half * 64 + gsw * 8,
                &Vt[bi ^ 1][half][sub * 512]);
      }
    }

    unsigned int w[4][8]; // [mt][gi]: P words for s = 32*mt + pattern

    // ---- pass A: mt 0,1 -> QK, softmax ----
    {
      f32x16 sa = {}, sb = {};
#pragma unroll
      for (int kc = 0; kc < 4; kc++) {
        const bf16x8 kf0 = *(const bf16x8*)&Kt[bi][(l31)*64 + ((kc * 16 + hi * 8) ^ (l7 * 8))];
        const bf16x8 kf1 =
            *(const bf16x8*)&Kt[bi][(32 + l31) * 64 + ((kc * 16 + hi * 8) ^ (l7 * 8))];
        sa = __builtin_amdgcn_mfma_f32_32x32x16_bf16(kf0, aq[kc], sa, 0, 0, 0);
        sb = __builtin_amdgcn_mfma_f32_32x32x16_bf16(kf1, aq[kc], sb, 0, 0, 0);
      }
      {
        float p[16];
#pragma unroll
        for (int r2 = 0; r2 < 16; r2++) p[r2] = fast_exp2(sa[r2]);
        lc[0] += ((p[0] + p[1]) + (p[2] + p[3])) + ((p[8] + p[9]) + (p[10] + p[11]));
        lc[1] += ((p[4] + p[5]) + (p[6] + p[7])) + ((p[12] + p[13]) + (p[14] + p[15]));
#pragma unroll
        for (int gi = 0; gi < 8; gi++) w[0][gi] = pkbf(p[2 * gi], p[2 * gi + 1]);
      }
      {
        float p[16];
#pragma unroll
        for (int r2 = 0; r2 < 16; r2++) p[r2] = fast_exp2(sb[r2]);
        lc[2] += ((p[0] + p[1]) + (p[2] + p[3])) + ((p[8] + p[9]) + (p[10] + p[11]));
        lc[3] += ((p[4] + p[5]) + (p[6] + p[7])) + ((p[12] + p[13]) + (p[14] + p[15]));
#pragma unroll
        for (int gi = 0; gi < 8; gi++) w[1][gi] = pkbf(p[2 * gi], p[2 * gi + 1]);
      }
    }

    // ---- pass B: mt 2,3 -> QK, softmax ----
    {
      f32x16 sa = {}, sb = {};
#pragma unroll
      for (int kc = 0; kc < 4; kc++) {
        const bf16x8 kf0 =
            *(const bf16x8*)&Kt[bi][(64 + l31) * 64 + ((kc * 16 + hi * 8) ^ (l7 * 8))];
        const bf16x8 kf1 =
            *(const bf16x8*)&Kt[bi][(96 + l31) * 64 + ((kc * 16 + hi * 8) ^ (l7 * 8))];
        sa = __builtin_amdgcn_mfma_f32_32x32x16_bf16(kf0, aq[kc], sa, 0, 0, 0);
        sb = __builtin_amdgcn_mfma_f32_32x32x16_bf16(kf1, aq[kc], sb, 0, 0, 0);
      }
      {
        float p[16];
#pragma unroll
        for (int r2 = 0; r2 < 16; r2++) p[r2] = fast_exp2(sa[r2]);
        lc[0] += ((p[0] + p[1]) + (p[2] + p[3])) + ((p[8] + p[9]) + (p[10] + p[11]));
        lc[1] += ((p[4] + p[5]) + (p[6] + p[7])) + ((p[12] + p[13]) + (p[14] + p[15]));
#pragma unroll
        for (int gi = 0; gi < 8; gi++) w[2][gi] = pkbf(p[2 * gi], p[2 * gi + 1]);
      }
      {
        float p[16];
#pragma unroll
        for (int r2 = 0; r2 < 16; r2++) p[r2] = fast_exp2(sb[r2]);
        lc[2] += ((p[0] + p[1]) + (p[2] + p[3])) + ((p[8] + p[9]) + (p[10] + p[11]));
        lc[3] += ((p[4] + p[5]) + (p[6] + p[7])) + ((p[12] + p[13]) + (p[14] + p[15]));
#pragma unroll
        for (int gi = 0; gi < 8; gi++) w[3][gi] = pkbf(p[2 * gi], p[2 * gi + 1]);
      }
    }

    // ---- PV: O^T += V^T (A) @ P^T (B), 8 s-chunks ----
#pragma unroll
    for (int sc = 0; sc < 8; sc++) {
      const int n0i = 2 * sc, n1i = 2 * sc + 1;
      const int mt0 = n0i >> 2, b0 = n0i & 3;
      const int mt1 = n1i >> 2, b1 = n1i & 3;
      const auto rA = __builtin_amdgcn_permlane32_swap(w[mt0][2 * b0], w[mt1][2 * b1],
                                                       false, false);
      const auto rB = __builtin_amdgcn_permlane32_swap(w[mt0][2 * b0 + 1], w[mt1][2 * b1 + 1],
                                                       false, false);
      union { unsigned int u[4]; bf16x8 v; } pb;
      pb.u[0] = rA[0]; // k = sc*16+hi*8 + {0,1}
      pb.u[1] = rB[0]; // + {2,3}
      pb.u[2] = rA[1]; // + {4,5}
      pb.u[3] = rB[1]; // + {6,7}
      const int half = sc >> 2, sch = sc & 3;
#pragma unroll
      for (int dt = 0; dt < 2; dt++) {
        const bf16x8 vf = *(const bf16x8*)&Vt[bi][half][(dt * 32 + l31) * 64 +
                                                       ((sch * 16 + hi * 8) ^ (l7 * 8))];
        o_acc[dt] = __builtin_amdgcn_mfma_f32_32x32x16_bf16(vf, pb.v, o_acc[dt], 0, 0, 0);
      }
    }
  }

  // epilogue: lanes l and l|32 hold complementary s-subsets of the same qrow
  float lsum = (lc[0] + lc[1]) + (lc[2] + lc[3]);
  const float l_i = lsum + __shfl_xor(lsum, 32, 64);
  const float inv = 1.0f / l_i;
  unsigned short* orow = O + ((size_t)(b * SEQ + qrow)) * H + h * 64;
#pragma unroll
  for (int dt = 0; dt < 2; dt++)
#pragma unroll
    for (int rg = 0; rg < 4; rg++) {
      uint2 d;
      d.x = pkbf(o_acc[dt][4 * rg + 0] * inv, o_acc[dt][4 * rg + 1] * inv);
      d.y = pkbf(o_acc[dt][4 * rg + 2] * inv, o_acc[dt][4 * rg + 3] * inv);
      *(uint2*)&orow[dt * 32 + 8 * rg + 4 * hi] = d;
    }
}

// ---------------------------------------------------------------------------
extern "C" void kernel_launch(void* const* d_in, const int* in_sizes, int n_in,
                              void* d_out, int out_size, void* d_ws, size_t ws_size,
                              hipStream_t stream) {
  const float* x = (const float*)d_in[0];
  const float* Wq = (const float*)d_in[1];
  const float* Wk = (const float*)d_in[2];
  const float* Wv = (const float*)d_in[3];
  const float* Wo = (const float*)d_in[4];
  const float* bo = (const float*)d_in[5];
  const float* gamma = (const float*)d_in[6];
  const float* beta = (const float*)d_in[7];
  float* out = (float*)d_out;

  unsigned short* ws = (unsigned short*)d_ws;
  unsigned short* xn = ws;                              // 4096*1024
  unsigned short* wcat = xn + (size_t)M_TOT * H;        // 4*1024*1024 (Wq,Wk,Wv,Wo)
  unsigned short* wob = wcat + (size_t)3 * H * H;
  unsigned short* qkb = wcat + (size_t)4 * H * H;       // 4096*2048 (Q | K)
  unsigned short* vtb = qkb + (size_t)M_TOT * 2048;     // 2*1024*2048 (V^T)
  unsigned short* atb = vtb + (size_t)BATCH * H * SEQ;  // 4096*1024

  ln_cast_kernel<<<M_TOT + 4096, 256, 0, stream>>>(x, gamma, beta, xn, Wq, Wk, Wv, Wo,
                                                   wcat);
  // QKV: 32 M-blocks x 24 N-blocks, XCD-supertiled (3 N-blocks per XCD)
  gemm128p<0, 3><<<(M_TOT / 128) * (NQKV / 128), 256, 0, stream>>>(
      xn, wcat, qkb, vtb, nullptr, nullptr, nullptr);
  // attn: 512 blocks (128-row q-tiles), XCD-supertiled (4 (b,h) combos per XCD)
  attn_kernel<<<(SEQ / 128) * NHEAD * BATCH, 256, 0, stream>>>(qkb, vtb, atb);
  // proj: 64 M-blocks x 8 N-blocks = 512 blocks (2 blocks/CU)
  proj64p<<<(M_TOT / 64) * (H / 128), 256, 0, stream>>>(atb, wob, bo, x, out);
}